// Round 1
// baseline (224.960 us; speedup 1.0000x reference)
//
#include <hip/hip_runtime.h>
#include <stdint.h>

typedef unsigned short u16;
typedef unsigned int u32;

#define NTOK 2048
#define CDIM 1024
#define BSZ  4
#define MTOT (BSZ * NTOK)
#define QKVD 3072
#define SM_SCALE 0.02209708691207961f  // 1/sqrt(2048)

typedef __bf16 bf16x8 __attribute__((ext_vector_type(8)));
typedef float f32x4 __attribute__((ext_vector_type(4)));

__device__ __forceinline__ u16 f2bf(float f) {
  u32 u = __float_as_uint(f);
  u += 0x7fffu + ((u >> 16) & 1u);   // round-to-nearest-even
  return (u16)(u >> 16);
}

// ---------------- W fp32 -> bf16 convert ----------------
__global__ __launch_bounds__(256) void wconv_kernel(const float* __restrict__ W,
                                                    u16* __restrict__ Wb, int n8) {
  int i = blockIdx.x * 256 + threadIdx.x;
  if (i >= n8) return;
  const float4* p = (const float4*)W + (size_t)i * 2;
  float4 a = p[0], b = p[1];
  uint4 o;
  o.x = (u32)f2bf(a.x) | ((u32)f2bf(a.y) << 16);
  o.y = (u32)f2bf(a.z) | ((u32)f2bf(a.w) << 16);
  o.z = (u32)f2bf(b.x) | ((u32)f2bf(b.y) << 16);
  o.w = (u32)f2bf(b.z) | ((u32)f2bf(b.w) << 16);
  ((uint4*)Wb)[i] = o;
}

// ---------------- transpose + LayerNorm: x[B,C,N] -> h[B*N, C] bf16 ----------------
// block: one batch b, 32 tokens. 512 threads.
__global__ __launch_bounds__(512) void ln_kernel(const float* __restrict__ x,
                                                 const float* __restrict__ gamma,
                                                 const float* __restrict__ beta,
                                                 u16* __restrict__ h) {
  int blk = blockIdx.x;          // BSZ * (NTOK/32) = 256
  int b = blk >> 6;
  int n0 = (blk & 63) << 5;
  int t = threadIdx.x;
  int nl = t & 31;               // token lane
  int cp = t >> 5;               // 0..15 c-partition
  const float* xb = x + (size_t)b * CDIM * NTOK + n0 + nl;

  float s = 0.f, ss = 0.f;
  for (int k = 0; k < 64; ++k) {
    float v = xb[(size_t)(cp + (k << 4)) * NTOK];
    s += v; ss += v * v;
  }
  __shared__ float ps[16][32], pss[16][32];
  __shared__ float mean_s[32], rstd_s[32];
  ps[cp][nl] = s; pss[cp][nl] = ss;
  __syncthreads();
  if (t < 32) {
    float m = 0.f, q = 0.f;
#pragma unroll
    for (int p = 0; p < 16; ++p) { m += ps[p][t]; q += pss[p][t]; }
    float mu = m * (1.f / CDIM);
    float var = q * (1.f / CDIM) - mu * mu;
    mean_s[t] = mu;
    rstd_s[t] = rsqrtf(var + 1e-5f);
  }
  __syncthreads();
  float mu_n = mean_s[nl], rs_n = rstd_s[nl];

  __shared__ float tile[64][33];
  int tn = t >> 4, cl = t & 15;
  for (int kk = 0; kk < 16; ++kk) {
    __syncthreads();
#pragma unroll
    for (int i = 0; i < 4; ++i) {
      int c = (kk << 6) + (cp << 2) + i;
      float v = xb[(size_t)c * NTOK];
      tile[(cp << 2) + i][nl] = (v - mu_n) * rs_n * gamma[c] + beta[c];
    }
    __syncthreads();
    uint2 pk;
    pk.x = (u32)f2bf(tile[(cl << 2) + 0][tn]) | ((u32)f2bf(tile[(cl << 2) + 1][tn]) << 16);
    pk.y = (u32)f2bf(tile[(cl << 2) + 2][tn]) | ((u32)f2bf(tile[(cl << 2) + 3][tn]) << 16);
    *(uint2*)&h[(size_t)(b * NTOK + n0 + tn) * CDIM + (kk << 6) + (cl << 2)] = pk;
  }
}

// ---------------- bf16 GEMM, B^T layout (both operands K-major) ----------------
// C[row,col] = sum_k A[row,k] * B[col,k]; 128x128 tile, BK=64, 4 waves.
__device__ __forceinline__ void gld_lds16(const void* g, void* l) {
  __builtin_amdgcn_global_load_lds(
      (const __attribute__((address_space(1))) void*)g,
      (__attribute__((address_space(3))) void*)l, 16, 0, 0);
}

template <int EPI>
__global__ __launch_bounds__(256) void gemm_bt_kernel(
    const u16* __restrict__ A, int lda, long sA,
    const u16* __restrict__ B, int ldb, long sB, int K,
    const float* __restrict__ bias,   // EPI0
    const float* __restrict__ pos,    // EPI1
    u16* __restrict__ Cb, int ldc, long sC,  // EPI0/1 bf16 out
    u16* __restrict__ VT,             // EPI0: transposed v out [b][c][j]
    float* __restrict__ CT, long sCT) // EPI2: f32 out [col*NTOK + row]
{
  const int bz = blockIdx.z;
  A += (size_t)bz * sA;
  B += (size_t)bz * sB;
  const int bm0 = blockIdx.x * 128;
  const int bn0 = blockIdx.y * 128;
  const int t = threadIdx.x;
  const int wave = t >> 6;
  const int wm = wave >> 1, wn = wave & 1;
  const int lr = t & 15, lk = (t & 63) >> 4;

  __shared__ u16 As[128 * 64];
  __shared__ u16 Bs[128 * 64];

  f32x4 acc[4][4];
#pragma unroll
  for (int m = 0; m < 4; ++m)
#pragma unroll
    for (int n = 0; n < 4; ++n) acc[m][n] = (f32x4){0.f, 0.f, 0.f, 0.f};

  const int srow = t >> 3;             // 0..31 within issue
  const int scol = (t & 7) << 3;       // bf16 col offset
  const u16* Ag = A + (size_t)(bm0 + srow) * lda + scol;
  const u16* Bg = B + (size_t)(bn0 + srow) * ldb + scol;
  char* Al = (char*)As + ((wave * 64) << 4);
  char* Bl = (char*)Bs + ((wave * 64) << 4);

  const int nk = K >> 6;
  for (int kt = 0; kt < nk; ++kt) {
    const int k0 = kt << 6;
    __syncthreads();
#pragma unroll
    for (int i = 0; i < 4; ++i) {
      gld_lds16(Ag + (size_t)(i * 32) * lda + k0, Al + i * 4096);
      gld_lds16(Bg + (size_t)(i * 32) * ldb + k0, Bl + i * 4096);
    }
    __syncthreads();
#pragma unroll
    for (int ks = 0; ks < 2; ++ks) {
      bf16x8 av[4], bv[4];
#pragma unroll
      for (int m = 0; m < 4; ++m)
        av[m] = *(const bf16x8*)&As[(wm * 64 + m * 16 + lr) * 64 + ks * 32 + lk * 8];
#pragma unroll
      for (int n = 0; n < 4; ++n)
        bv[n] = *(const bf16x8*)&Bs[(wn * 64 + n * 16 + lr) * 64 + ks * 32 + lk * 8];
#pragma unroll
      for (int m = 0; m < 4; ++m)
#pragma unroll
        for (int n = 0; n < 4; ++n)
          acc[m][n] = __builtin_amdgcn_mfma_f32_16x16x32_bf16(av[m], bv[n], acc[m][n], 0, 0, 0);
    }
  }

  // epilogue: lane holds col = ..+lr fixed, rows (lk*4 + r), r=0..3 consecutive
#pragma unroll
  for (int m = 0; m < 4; ++m) {
    const int row = bm0 + wm * 64 + m * 16 + lk * 4;
#pragma unroll
    for (int n = 0; n < 4; ++n) {
      const int col = bn0 + wn * 64 + n * 16 + lr;
      f32x4 v = acc[m][n];
      if (EPI == 0) {
        const float bb = bias[col];
        if (col < 2 * CDIM) {
#pragma unroll
          for (int r = 0; r < 4; ++r)
            Cb[(size_t)(row + r) * ldc + col] = f2bf(v[r] + bb);
        } else {
          // v-part: write transposed vT[b][c][j], 4 consecutive j per lane
          const int bq = row >> 11;
          const int j = row & (NTOK - 1);
          const int c2 = col - 2 * CDIM;
          uint2 pk;
          pk.x = (u32)f2bf(v[0] + bb) | ((u32)f2bf(v[1] + bb) << 16);
          pk.y = (u32)f2bf(v[2] + bb) | ((u32)f2bf(v[3] + bb) << 16);
          *(uint2*)&VT[((size_t)bq * CDIM + c2) * NTOK + j] = pk;
        }
      } else if (EPI == 1) {
        u16* Cp = Cb + (size_t)bz * sC;
#pragma unroll
        for (int r = 0; r < 4; ++r) {
          float sv = v[r] * SM_SCALE + pos[(size_t)(row + r) * NTOK + col];
          Cp[(size_t)(row + r) * ldc + col] = f2bf(sv);
        }
      } else {
        // transposed f32 write: out[col*NTOK + row..row+3], 16B aligned
        float* o = CT + (size_t)bz * sCT + (size_t)col * NTOK + row;
        *(f32x4*)o = v;
      }
    }
  }
}

// ---------------- row softmax, in place on bf16 [8192, 2048] ----------------
__global__ __launch_bounds__(256) void softmax_kernel(u16* __restrict__ S) {
  const size_t row = blockIdx.x;
  u16* Sr = S + row * NTOK;
  const int t = threadIdx.x;
  const int lane = t & 63, wv = t >> 6;
  uint4 d = ((const uint4*)Sr)[t];
  float v[8];
#pragma unroll
  for (int i = 0; i < 4; ++i) {
    u32 w = ((const u32*)&d)[i];
    v[2 * i]     = __uint_as_float(w << 16);
    v[2 * i + 1] = __uint_as_float(w & 0xffff0000u);
  }
  float mx = v[0];
#pragma unroll
  for (int i = 1; i < 8; ++i) mx = fmaxf(mx, v[i]);
#pragma unroll
  for (int o = 32; o > 0; o >>= 1) mx = fmaxf(mx, __shfl_xor(mx, o, 64));
  __shared__ float r1[4], r2[4];
  if (lane == 0) r1[wv] = mx;
  __syncthreads();
  mx = fmaxf(fmaxf(r1[0], r1[1]), fmaxf(r1[2], r1[3]));
  float e[8], s = 0.f;
#pragma unroll
  for (int i = 0; i < 8; ++i) { e[i] = __expf(v[i] - mx); s += e[i]; }
#pragma unroll
  for (int o = 32; o > 0; o >>= 1) s += __shfl_xor(s, o, 64);
  if (lane == 0) r2[wv] = s;
  __syncthreads();
  s = r2[0] + r2[1] + r2[2] + r2[3];
  const float inv = 1.f / s;
  uint4 o4;
#pragma unroll
  for (int i = 0; i < 4; ++i)
    ((u32*)&o4)[i] = (u32)f2bf(e[2 * i] * inv) | ((u32)f2bf(e[2 * i + 1] * inv) << 16);
  ((uint4*)Sr)[t] = o4;
}

extern "C" void kernel_launch(void* const* d_in, const int* in_sizes, int n_in,
                              void* d_out, int out_size, void* d_ws, size_t ws_size,
                              hipStream_t stream) {
  const float* x     = (const float*)d_in[0];
  const float* pos   = (const float*)d_in[1];
  const float* gamma = (const float*)d_in[2];
  const float* beta  = (const float*)d_in[3];
  const float* W     = (const float*)d_in[4];
  const float* bias  = (const float*)d_in[5];
  float* out = (float*)d_out;
  char* ws = (char*)d_ws;

  // workspace layout (118 MB total)
  u16* Wb  = (u16*)(ws);                  //  6 MB  [3072,1024] bf16
  u16* h   = (u16*)(ws + (6ll << 20));    // 16 MB  [8192,1024] bf16
  u16* qkv = (u16*)(ws + (22ll << 20));   // 48 MB  [8192,3072] bf16 (q,k cols used)
  u16* vT  = (u16*)(ws + (70ll << 20));   // 16 MB  [4][1024][2048] bf16
  u16* S   = (u16*)(ws + (86ll << 20));   // 32 MB  [4][2048][2048] bf16 (scores->P in place)

  wconv_kernel<<<dim3((QKVD * CDIM / 8 + 255) / 256), 256, 0, stream>>>(W, Wb, QKVD * CDIM / 8);
  ln_kernel<<<dim3(BSZ * (NTOK / 32)), 512, 0, stream>>>(x, gamma, beta, h);

  // qkv = h @ W^T + b  (M=8192, N=3072, K=1024); v written transposed into vT
  gemm_bt_kernel<0><<<dim3(MTOT / 128, QKVD / 128, 1), 256, 0, stream>>>(
      h, CDIM, 0, Wb, CDIM, 0, CDIM,
      bias, nullptr, qkv, QKVD, 0, vT, nullptr, 0);

  // S = q @ k^T * scale + position  (per batch M=N=2048, K=1024)
  gemm_bt_kernel<1><<<dim3(NTOK / 128, NTOK / 128, BSZ), 256, 0, stream>>>(
      qkv, QKVD, (long)NTOK * QKVD, qkv + CDIM, QKVD, (long)NTOK * QKVD, CDIM,
      nullptr, pos, S, NTOK, (long)NTOK * NTOK, nullptr, nullptr, 0);

  softmax_kernel<<<dim3(MTOT), 256, 0, stream>>>(S);

  // out = P @ vT^T, written transposed to [B, C, N] f32
  gemm_bt_kernel<2><<<dim3(NTOK / 128, CDIM / 128, BSZ), 256, 0, stream>>>(
      S, NTOK, (long)NTOK * NTOK, vT, NTOK, (long)CDIM * NTOK, NTOK,
      nullptr, nullptr, nullptr, 0, 0, nullptr, out, (long)CDIM * NTOK);
}

// Round 2
// 213.996 us; speedup vs baseline: 1.0512x; 1.0512x over previous
//
#include <hip/hip_runtime.h>
#include <stdint.h>

typedef unsigned short u16;
typedef unsigned int u32;

#define NTOK 2048
#define CDIM 1024
#define BSZ  4
#define MTOT (BSZ * NTOK)
#define QKVD 3072
#define SM_SCALE 0.02209708691207961f  // 1/sqrt(2048)

typedef __bf16 bf16x8 __attribute__((ext_vector_type(8)));
typedef float f32x4 __attribute__((ext_vector_type(4)));

__device__ __forceinline__ u16 f2bf(float f) {
  u32 u = __float_as_uint(f);
  u += 0x7fffu + ((u >> 16) & 1u);   // round-to-nearest-even
  return (u16)(u >> 16);
}

// ---------------- W fp32 -> bf16 convert ----------------
__global__ __launch_bounds__(256) void wconv_kernel(const float* __restrict__ W,
                                                    u16* __restrict__ Wb, int n8) {
  int i = blockIdx.x * 256 + threadIdx.x;
  if (i >= n8) return;
  const float4* p = (const float4*)W + (size_t)i * 2;
  float4 a = p[0], b = p[1];
  uint4 o;
  o.x = (u32)f2bf(a.x) | ((u32)f2bf(a.y) << 16);
  o.y = (u32)f2bf(a.z) | ((u32)f2bf(a.w) << 16);
  o.z = (u32)f2bf(b.x) | ((u32)f2bf(b.y) << 16);
  o.w = (u32)f2bf(b.z) | ((u32)f2bf(b.w) << 16);
  ((uint4*)Wb)[i] = o;
}

// ---------------- transpose + LayerNorm: x[B,C,N] -> h[B*N, C] bf16 ----------------
__global__ __launch_bounds__(512) void ln_kernel(const float* __restrict__ x,
                                                 const float* __restrict__ gamma,
                                                 const float* __restrict__ beta,
                                                 u16* __restrict__ h) {
  int blk = blockIdx.x;          // BSZ * (NTOK/32) = 256
  int b = blk >> 6;
  int n0 = (blk & 63) << 5;
  int t = threadIdx.x;
  int nl = t & 31;               // token lane
  int cp = t >> 5;               // 0..15 c-partition
  const float* xb = x + (size_t)b * CDIM * NTOK + n0 + nl;

  float s = 0.f, ss = 0.f;
  for (int k = 0; k < 64; ++k) {
    float v = xb[(size_t)(cp + (k << 4)) * NTOK];
    s += v; ss += v * v;
  }
  __shared__ float ps[16][32], pss[16][32];
  __shared__ float mean_s[32], rstd_s[32];
  ps[cp][nl] = s; pss[cp][nl] = ss;
  __syncthreads();
  if (t < 32) {
    float m = 0.f, q = 0.f;
#pragma unroll
    for (int p = 0; p < 16; ++p) { m += ps[p][t]; q += pss[p][t]; }
    float mu = m * (1.f / CDIM);
    float var = q * (1.f / CDIM) - mu * mu;
    mean_s[t] = mu;
    rstd_s[t] = rsqrtf(var + 1e-5f);
  }
  __syncthreads();
  float mu_n = mean_s[nl], rs_n = rstd_s[nl];

  __shared__ float tile[64][33];
  int tn = t >> 4, cl = t & 15;
  for (int kk = 0; kk < 16; ++kk) {
    __syncthreads();
#pragma unroll
    for (int i = 0; i < 4; ++i) {
      int c = (kk << 6) + (cp << 2) + i;
      float v = xb[(size_t)c * NTOK];
      tile[(cp << 2) + i][nl] = (v - mu_n) * rs_n * gamma[c] + beta[c];
    }
    __syncthreads();
    uint2 pk;
    pk.x = (u32)f2bf(tile[(cl << 2) + 0][tn]) | ((u32)f2bf(tile[(cl << 2) + 1][tn]) << 16);
    pk.y = (u32)f2bf(tile[(cl << 2) + 2][tn]) | ((u32)f2bf(tile[(cl << 2) + 3][tn]) << 16);
    *(uint2*)&h[(size_t)(b * NTOK + n0 + tn) * CDIM + (kk << 6) + (cl << 2)] = pk;
  }
}

// ---------------- pipelined bf16 GEMM, B^T layout ----------------
// C[row,col] = sum_k A[row,k]*B[col,k]. BM=256, BN=128, BK=64, 8 waves (4Mx2N).
// 2-tile prefetch distance, counted vmcnt(6), XOR-swizzled LDS, raw barriers.
__device__ __forceinline__ void gld_lds16(const void* g, void* l) {
  __builtin_amdgcn_global_load_lds(
      (const __attribute__((address_space(1))) void*)g,
      (__attribute__((address_space(3))) void*)l, 16, 0, 0);
}

// stage one 128x64(bf16)=16KB half-tile; LDS dest linear, source col pre-swizzled
__device__ __forceinline__ void stage_half(const char* g, long ldb, char* l, int t) {
  const int wv = t >> 6;
#pragma unroll
  for (int i = 0; i < 2; ++i) {
    int p = (t << 4) + (i << 13);
    int r = p >> 7;
    int cb = (p & 127) ^ ((r & 7) << 4);
    gld_lds16(g + (long)r * ldb + cb, l + (wv << 10) + (i << 13));
  }
}

template <int EPI>
__global__ __launch_bounds__(512) void gemm8p_kernel(
    const u16* __restrict__ A, int lda, long sA,
    const u16* __restrict__ B, int ldb, long sB, int K,
    const float* __restrict__ bias,   // EPI0
    const float* __restrict__ pos,    // EPI1
    u16* __restrict__ Cb, int ldc, long sC,  // EPI0/1 bf16 out
    u16* __restrict__ VT,             // EPI0: transposed v out [b][c][j]
    float* __restrict__ CT, long sCT) // EPI2: f32 out [col*NTOK + row]
{
  // LDS: A bufs 2x32KB @0, B bufs 2x16KB @65536. total 96KB
  __shared__ char smem[98304];
  const int bz = blockIdx.z;
  A += (size_t)bz * sA;
  B += (size_t)bz * sB;

  // bijective XCD swizzle (all our grids have nwg % 8 == 0)
  const int nwg = gridDim.x * gridDim.y;
  const int orig = blockIdx.y * gridDim.x + blockIdx.x;
  const int wg = (orig & 7) * (nwg >> 3) + (orig >> 3);
  const int bm0 = (wg % gridDim.x) * 256;
  const int bn0 = (wg / gridDim.x) * 128;

  const int t = threadIdx.x;
  const int wave = t >> 6;
  const int wm = wave >> 1;      // 0..3 : rows wm*64
  const int wn = wave & 1;       // 0..1 : cols wn*64
  const int lr = t & 15, lk = (t & 63) >> 4;

  const long lda2 = (long)lda * 2, ldb2 = (long)ldb * 2;
  const char* Agb = (const char*)(A + (size_t)bm0 * lda);
  const char* Bgb = (const char*)(B + (size_t)bn0 * ldb);

  f32x4 acc[4][4];
#pragma unroll
  for (int m = 0; m < 4; ++m)
#pragma unroll
    for (int n = 0; n < 4; ++n) acc[m][n] = (f32x4){0.f, 0.f, 0.f, 0.f};

  const int nt = K >> 6;
  // prologue: stage tile0 (A0,A1,B) and tile1 (A0,A1,B)
  stage_half(Agb,                   lda2, smem,         t);
  stage_half(Agb + (long)128 * lda2, lda2, smem + 16384, t);
  stage_half(Bgb,                   ldb2, smem + 65536, t);
  if (nt > 1) {
    stage_half(Agb + 128,                    lda2, smem + 32768, t);
    stage_half(Agb + (long)128 * lda2 + 128, lda2, smem + 49152, t);
    stage_half(Bgb + 128,                    ldb2, smem + 81920, t);
    asm volatile("s_waitcnt vmcnt(6)" ::: "memory");
  } else {
    asm volatile("s_waitcnt vmcnt(0)" ::: "memory");
  }
  __builtin_amdgcn_sched_barrier(0);
  __builtin_amdgcn_s_barrier();

  for (int kt = 0; kt < nt; ++kt) {
    const int cur = kt & 1;
    const char* Ab = smem + (cur << 15);
    const char* Bb = smem + 65536 + (cur << 14);

    // front-load ALL fragments: buffer is fully consumed after cluster-0 barrier
    bf16x8 av[4][2], bv[4][2];
#pragma unroll
    for (int m = 0; m < 4; ++m)
#pragma unroll
      for (int ks = 0; ks < 2; ++ks) {
        const int row = wm * 64 + m * 16 + lr;
        const int cby = ((ks << 6) + (lk << 4)) ^ ((lr & 7) << 4);
        av[m][ks] = *(const bf16x8*)(Ab + row * 128 + cby);
      }
#pragma unroll
    for (int n = 0; n < 4; ++n)
#pragma unroll
      for (int ks = 0; ks < 2; ++ks) {
        const int row = wn * 64 + n * 16 + lr;
        const int cby = ((ks << 6) + (lk << 4)) ^ ((lr & 7) << 4);
        bv[n][ks] = *(const bf16x8*)(Bb + row * 128 + cby);
      }

    auto cluster = [&](int m) {
      __builtin_amdgcn_s_setprio(1);
#pragma unroll
      for (int n = 0; n < 4; ++n)
#pragma unroll
        for (int ks = 0; ks < 2; ++ks)
          acc[m][n] = __builtin_amdgcn_mfma_f32_16x16x32_bf16(av[m][ks], bv[n][ks],
                                                              acc[m][n], 0, 0, 0);
      __builtin_amdgcn_s_setprio(0);
    };

    cluster(0);
    // all 16 ds_reads drained (all waves) before re-staging this buffer
    asm volatile("s_waitcnt lgkmcnt(0)" ::: "memory");
    __builtin_amdgcn_sched_barrier(0);
    __builtin_amdgcn_s_barrier();

    const int kt2 = kt + 2;
    const bool st2 = kt2 < nt;
    const char* An2 = Agb + (long)kt2 * 128;
    const char* Bn2 = Bgb + (long)kt2 * 128;
    char* Ab2 = (char*)smem + (cur << 15);
    char* Bb2 = (char*)smem + 65536 + (cur << 14);

    if (st2) stage_half(An2, lda2, Ab2, t);
    cluster(1);
    if (st2) stage_half(An2 + (long)128 * lda2, lda2, Ab2 + 16384, t);
    cluster(2);
    if (st2) stage_half(Bn2, ldb2, Bb2, t);
    cluster(3);

    if (st2) {
      asm volatile("s_waitcnt vmcnt(6)" ::: "memory");   // tile t+1 fully landed
    } else if (kt + 1 < nt) {
      asm volatile("s_waitcnt vmcnt(0)" ::: "memory");   // tail: drain everything
    }
    __builtin_amdgcn_sched_barrier(0);
    __builtin_amdgcn_s_barrier();
  }

  // epilogue: lane holds col fixed, rows lk*4 + r consecutive
#pragma unroll
  for (int m = 0; m < 4; ++m) {
    const int row = bm0 + wm * 64 + m * 16 + (lk << 2);
#pragma unroll
    for (int n = 0; n < 4; ++n) {
      const int col = bn0 + wn * 64 + n * 16 + lr;
      f32x4 v = acc[m][n];
      if (EPI == 0) {
        const float bb = bias[col];
        if (col < 2 * CDIM) {
#pragma unroll
          for (int r = 0; r < 4; ++r)
            Cb[(size_t)(row + r) * ldc + col] = f2bf(v[r] + bb);
        } else {
          const int bq = row >> 11;
          const int j = row & (NTOK - 1);
          const int c2 = col - 2 * CDIM;
          uint2 pk;
          pk.x = (u32)f2bf(v[0] + bb) | ((u32)f2bf(v[1] + bb) << 16);
          pk.y = (u32)f2bf(v[2] + bb) | ((u32)f2bf(v[3] + bb) << 16);
          *(uint2*)&VT[((size_t)bq * CDIM + c2) * NTOK + j] = pk;
        }
      } else if (EPI == 1) {
        u16* Cp = Cb + (size_t)bz * sC;
#pragma unroll
        for (int r = 0; r < 4; ++r) {
          float sv = v[r] * SM_SCALE + pos[(size_t)(row + r) * NTOK + col];
          Cp[(size_t)(row + r) * ldc + col] = f2bf(sv);
        }
      } else {
        float* o = CT + (size_t)bz * sCT + (size_t)col * NTOK + row;
        *(f32x4*)o = v;
      }
    }
  }
}

// ---------------- row softmax, in place on bf16 [8192, 2048] ----------------
__global__ __launch_bounds__(256) void softmax_kernel(u16* __restrict__ S) {
  const size_t row = blockIdx.x;
  u16* Sr = S + row * NTOK;
  const int t = threadIdx.x;
  const int lane = t & 63, wv = t >> 6;
  uint4 d = ((const uint4*)Sr)[t];
  float v[8];
#pragma unroll
  for (int i = 0; i < 4; ++i) {
    u32 w = ((const u32*)&d)[i];
    v[2 * i]     = __uint_as_float(w << 16);
    v[2 * i + 1] = __uint_as_float(w & 0xffff0000u);
  }
  float mx = v[0];
#pragma unroll
  for (int i = 1; i < 8; ++i) mx = fmaxf(mx, v[i]);
#pragma unroll
  for (int o = 32; o > 0; o >>= 1) mx = fmaxf(mx, __shfl_xor(mx, o, 64));
  __shared__ float r1[4], r2[4];
  if (lane == 0) r1[wv] = mx;
  __syncthreads();
  mx = fmaxf(fmaxf(r1[0], r1[1]), fmaxf(r1[2], r1[3]));
  float e[8], s = 0.f;
#pragma unroll
  for (int i = 0; i < 8; ++i) { e[i] = __expf(v[i] - mx); s += e[i]; }
#pragma unroll
  for (int o = 32; o > 0; o >>= 1) s += __shfl_xor(s, o, 64);
  if (lane == 0) r2[wv] = s;
  __syncthreads();
  s = r2[0] + r2[1] + r2[2] + r2[3];
  const float inv = 1.f / s;
  uint4 o4;
#pragma unroll
  for (int i = 0; i < 4; ++i)
    ((u32*)&o4)[i] = (u32)f2bf(e[2 * i] * inv) | ((u32)f2bf(e[2 * i + 1] * inv) << 16);
  ((uint4*)Sr)[t] = o4;
}

extern "C" void kernel_launch(void* const* d_in, const int* in_sizes, int n_in,
                              void* d_out, int out_size, void* d_ws, size_t ws_size,
                              hipStream_t stream) {
  const float* x     = (const float*)d_in[0];
  const float* pos   = (const float*)d_in[1];
  const float* gamma = (const float*)d_in[2];
  const float* beta  = (const float*)d_in[3];
  const float* W     = (const float*)d_in[4];
  const float* bias  = (const float*)d_in[5];
  float* out = (float*)d_out;
  char* ws = (char*)d_ws;

  // workspace layout (118 MB total)
  u16* Wb  = (u16*)(ws);                  //  6 MB  [3072,1024] bf16
  u16* h   = (u16*)(ws + (6ll << 20));    // 16 MB  [8192,1024] bf16
  u16* qkv = (u16*)(ws + (22ll << 20));   // 48 MB  [8192,3072] bf16 (q,k cols used)
  u16* vT  = (u16*)(ws + (70ll << 20));   // 16 MB  [4][1024][2048] bf16
  u16* S   = (u16*)(ws + (86ll << 20));   // 32 MB  [4][2048][2048] bf16

  wconv_kernel<<<dim3((QKVD * CDIM / 8 + 255) / 256), 256, 0, stream>>>(W, Wb, QKVD * CDIM / 8);
  ln_kernel<<<dim3(BSZ * (NTOK / 32)), 512, 0, stream>>>(x, gamma, beta, h);

  // qkv = h @ W^T + b  (M=8192, N=3072, K=1024); v written transposed into vT
  gemm8p_kernel<0><<<dim3(MTOT / 256, QKVD / 128, 1), 512, 0, stream>>>(
      h, CDIM, 0, Wb, CDIM, 0, CDIM,
      bias, nullptr, qkv, QKVD, 0, vT, nullptr, 0);

  // S = q @ k^T * scale + position  (per batch M=N=2048, K=1024)
  gemm8p_kernel<1><<<dim3(NTOK / 256, NTOK / 128, BSZ), 512, 0, stream>>>(
      qkv, QKVD, (long)NTOK * QKVD, qkv + CDIM, QKVD, (long)NTOK * QKVD, CDIM,
      nullptr, pos, S, NTOK, (long)NTOK * NTOK, nullptr, nullptr, 0);

  softmax_kernel<<<dim3(MTOT), 256, 0, stream>>>(S);

  // out = P @ vT^T, written transposed to [B, C, N] f32
  gemm8p_kernel<2><<<dim3(NTOK / 256, CDIM / 128, BSZ), 512, 0, stream>>>(
      S, NTOK, (long)NTOK * NTOK, vT, NTOK, (long)CDIM * NTOK, NTOK,
      nullptr, nullptr, nullptr, 0, 0, nullptr, out, (long)CDIM * NTOK);
}

// Round 3
// 193.910 us; speedup vs baseline: 1.1601x; 1.1036x over previous
//
#include <hip/hip_runtime.h>
#include <stdint.h>

typedef unsigned short u16;
typedef unsigned int u32;

#define NTOK 2048
#define CDIM 1024
#define BSZ  4
#define MTOT (BSZ * NTOK)
#define QKVD 3072
#define SM_SCALE 0.02209708691207961f  // 1/sqrt(2048)

typedef __bf16 bf16x8 __attribute__((ext_vector_type(8)));
typedef float f32x4 __attribute__((ext_vector_type(4)));

__device__ __forceinline__ u16 f2bf(float f) {
  u32 u = __float_as_uint(f);
  u += 0x7fffu + ((u >> 16) & 1u);   // round-to-nearest-even
  return (u16)(u >> 16);
}

// ---------------- W fp32 -> bf16 convert ----------------
__global__ __launch_bounds__(256) void wconv_kernel(const float* __restrict__ W,
                                                    u16* __restrict__ Wb, int n8) {
  int i = blockIdx.x * 256 + threadIdx.x;
  if (i >= n8) return;
  const float4* p = (const float4*)W + (size_t)i * 2;
  float4 a = p[0], b = p[1];
  uint4 o;
  o.x = (u32)f2bf(a.x) | ((u32)f2bf(a.y) << 16);
  o.y = (u32)f2bf(a.z) | ((u32)f2bf(a.w) << 16);
  o.z = (u32)f2bf(b.x) | ((u32)f2bf(b.y) << 16);
  o.w = (u32)f2bf(b.z) | ((u32)f2bf(b.w) << 16);
  ((uint4*)Wb)[i] = o;
}

// ---------------- transpose + LayerNorm: x[B,C,N] -> h[B*N, C] bf16 ----------------
__global__ __launch_bounds__(512) void ln_kernel(const float* __restrict__ x,
                                                 const float* __restrict__ gamma,
                                                 const float* __restrict__ beta,
                                                 u16* __restrict__ h) {
  int blk = blockIdx.x;          // BSZ * (NTOK/32) = 256
  int b = blk >> 6;
  int n0 = (blk & 63) << 5;
  int t = threadIdx.x;
  int nl = t & 31;               // token lane
  int cp = t >> 5;               // 0..15 c-partition
  const float* xb = x + (size_t)b * CDIM * NTOK + n0 + nl;

  float s = 0.f, ss = 0.f;
  for (int k = 0; k < 64; ++k) {
    float v = xb[(size_t)(cp + (k << 4)) * NTOK];
    s += v; ss += v * v;
  }
  __shared__ float ps[16][32], pss[16][32];
  __shared__ float mean_s[32], rstd_s[32];
  ps[cp][nl] = s; pss[cp][nl] = ss;
  __syncthreads();
  if (t < 32) {
    float m = 0.f, q = 0.f;
#pragma unroll
    for (int p = 0; p < 16; ++p) { m += ps[p][t]; q += pss[p][t]; }
    float mu = m * (1.f / CDIM);
    float var = q * (1.f / CDIM) - mu * mu;
    mean_s[t] = mu;
    rstd_s[t] = rsqrtf(var + 1e-5f);
  }
  __syncthreads();
  float mu_n = mean_s[nl], rs_n = rstd_s[nl];

  __shared__ float tile[64][33];
  int tn = t >> 4, cl = t & 15;
  for (int kk = 0; kk < 16; ++kk) {
    __syncthreads();
#pragma unroll
    for (int i = 0; i < 4; ++i) {
      int c = (kk << 6) + (cp << 2) + i;
      float v = xb[(size_t)c * NTOK];
      tile[(cp << 2) + i][nl] = (v - mu_n) * rs_n * gamma[c] + beta[c];
    }
    __syncthreads();
    uint2 pk;
    pk.x = (u32)f2bf(tile[(cl << 2) + 0][tn]) | ((u32)f2bf(tile[(cl << 2) + 1][tn]) << 16);
    pk.y = (u32)f2bf(tile[(cl << 2) + 2][tn]) | ((u32)f2bf(tile[(cl << 2) + 3][tn]) << 16);
    *(uint2*)&h[(size_t)(b * NTOK + n0 + tn) * CDIM + (kk << 6) + (cl << 2)] = pk;
  }
}

// ---------------- 4-phase pipelined bf16 GEMM, B^T layout ----------------
// C[row,col] = sum_k A[row,k]*B[col,k]. BM=256, BN=256|128, BK=64 (2 k-halves).
// Phase (ks,mp): ds_read subtile || stage region freed last barrier || BAR ||
// lgkm(0) || MFMA || BAR.  Counted vmcnt at tile entry only.
__device__ __forceinline__ void gld_lds16(const void* g, void* l) {
  __builtin_amdgcn_global_load_lds(
      (const __attribute__((address_space(1))) void*)g,
      (__attribute__((address_space(3))) void*)l, 16, 0, 0);
}

// stage a [128*NI rows][64B] k-half region; LDS linear, source slot-permuted
// LDS (row, s) holds global slot (s - (row>>1))&3  -> reader slot (lk+(row>>1))&3
template <int NI>
__device__ __forceinline__ void stage_reg(const char* g, long ld, char* lds, int t) {
  const long rbase = (long)(t >> 2) * ld + (((((t & 3) - (t >> 3)) & 3)) << 4);
#pragma unroll
  for (int i = 0; i < NI; ++i)
    gld_lds16(g + rbase + (long)i * 128 * ld,
              lds + ((t >> 6) << 10) + (i << 13));
}

template <int EPI, int BN>
__global__ __launch_bounds__(512, 2) void gemmp_kernel(
    const u16* __restrict__ A, int lda, long sA,
    const u16* __restrict__ B, int ldb, long sB, int K,
    const float* __restrict__ bias,   // EPI0
    const float* __restrict__ pos,    // EPI1
    u16* __restrict__ Cb, int ldc, long sC,  // EPI0/1 bf16 out
    u16* __restrict__ VT,             // EPI0: transposed v out [b][c][j]
    float* __restrict__ CT, long sCT) // EPI2: f32 out [col*NTOK + row]
{
  constexpr int GB  = (BN == 256) ? 2 : 1;   // gld per B-half per thread
  constexpr int MF  = (BN == 256) ? 8 : 4;   // m-frags per wave
  constexpr int MPP = MF / 2;                // m-frags per phase
  constexpr int ABUF = 65536;                // A: 2buf x 2half x 16KB
  constexpr int HB  = BN * 64;               // B half bytes
  __shared__ char smem[ABUF + 4 * HB];

  // chunked bijective XCD swizzle: xcd k owns m-chunk [k*MX, (k+1)*MX),
  // intra order m-fastest, then n, then z.
  const int GX = gridDim.x, GY = gridDim.y;
  const int hb = ((int)blockIdx.z * GY + blockIdx.y) * GX + blockIdx.x;
  const int MX = GX >> 3;
  const int k8 = hb & 7, j8 = hb >> 3;
  const int m = k8 * MX + (j8 % MX);
  const int rest = j8 / MX;
  const int n = rest % GY;
  const int bz = rest / GY;

  A += (size_t)bz * sA;
  B += (size_t)bz * sB;
  const int bm0 = m * 256;
  const int bn0 = n * BN;

  const int t = threadIdx.x;
  const int wave = t >> 6;
  const int wm = (BN == 256) ? (wave >> 2) : (wave >> 1);
  const int wn = (BN == 256) ? (wave & 3) : (wave & 1);
  const int MROW = wm * (MF * 16);
  const int NCOL = wn * 64;
  const int lr = t & 15, lk = (t & 63) >> 4;
  // per-lane fragment byte offset within a k-half region (bank-perfect)
  const int fragoff = lr * 64 + (((lk + (lr >> 1)) & 3) << 4);

  const long lda2 = (long)lda * 2, ldb2 = (long)ldb * 2;
  const char* Agb = (const char*)A + (size_t)bm0 * lda2;
  const char* Bgb = (const char*)B + (size_t)bn0 * ldb2;

#define STAGE_A(kt, h, cc) \
  stage_reg<2>(Agb + (long)(kt) * 128 + (h) * 64, lda2, smem + ((((cc) << 1) | (h)) << 14), t)
#define STAGE_B(kt, h, cc) \
  stage_reg<GB>(Bgb + (long)(kt) * 128 + (h) * 64, ldb2, smem + ABUF + ((((cc) << 1) | (h)) * HB), t)

  f32x4 acc[MF][4];
#pragma unroll
  for (int mm = 0; mm < MF; ++mm)
#pragma unroll
    for (int nn = 0; nn < 4; ++nn) acc[mm][nn] = (f32x4){0.f, 0.f, 0.f, 0.f};

  const int nt = K >> 6;   // assumed >= 4
  // prologue: tiles 0 and 1, region order Bk0, Ak0, Bk1, Ak1
  STAGE_B(0, 0, 0); STAGE_A(0, 0, 0); STAGE_B(0, 1, 0); STAGE_A(0, 1, 0);
  STAGE_B(1, 0, 1); STAGE_A(1, 0, 1); STAGE_B(1, 1, 1); STAGE_A(1, 1, 1);
  if (BN == 256) asm volatile("s_waitcnt vmcnt(8)" ::: "memory");
  else           asm volatile("s_waitcnt vmcnt(6)" ::: "memory");
  __builtin_amdgcn_sched_barrier(0);
  __builtin_amdgcn_s_barrier();
  __builtin_amdgcn_sched_barrier(0);

  bf16x8 av[MPP], bv[4];

#define DO_PHASE(KS, MP, STAGE_STMT)                                           \
  {                                                                            \
    if (MP == 0) {                                                             \
      const char* Bb = smem + ABUF + (((c << 1) | KS) * HB);                   \
      _Pragma("unroll") for (int nn = 0; nn < 4; ++nn)                         \
        bv[nn] = *(const bf16x8*)(Bb + (NCOL + nn * 16) * 64 + fragoff);       \
    }                                                                          \
    {                                                                          \
      const char* Ab = smem + (((c << 1) | KS) << 14);                         \
      _Pragma("unroll") for (int i = 0; i < MPP; ++i)                          \
        av[i] = *(const bf16x8*)(Ab + (MROW + (MP * MPP + i) * 16) * 64 + fragoff); \
    }                                                                          \
    STAGE_STMT;                                                                \
    __builtin_amdgcn_s_barrier();                                              \
    asm volatile("s_waitcnt lgkmcnt(0)" ::: "memory");                         \
    __builtin_amdgcn_sched_barrier(0);                                         \
    __builtin_amdgcn_s_setprio(1);                                             \
    _Pragma("unroll") for (int i = 0; i < MPP; ++i)                            \
      _Pragma("unroll") for (int nn = 0; nn < 4; ++nn)                         \
        acc[MP * MPP + i][nn] = __builtin_amdgcn_mfma_f32_16x16x32_bf16(       \
            av[i], bv[nn], acc[MP * MPP + i][nn], 0, 0, 0);                    \
    __builtin_amdgcn_s_setprio(0);                                             \
  }

  for (int u = 0; u < nt; ++u) {
    const int c = u & 1;
    // ph0: reads B-k0 + A-k0(first half); stages A-k1 of tile u+1 (freed end of u-1)
    DO_PHASE(0, 0, { if (u >= 1 && u + 1 < nt) STAGE_A(u + 1, 1, (u + 1) & 1); });
    __builtin_amdgcn_s_barrier();
    __builtin_amdgcn_sched_barrier(0);
    // ph1: A-k0 second half; stage B-k0(u+2) (freed at ph0 barrier)
    DO_PHASE(0, 1, { if (u + 2 < nt) STAGE_B(u + 2, 0, c); });
    __builtin_amdgcn_s_barrier();
    __builtin_amdgcn_sched_barrier(0);
    // ph2: B-k1 + A-k1 first half; stage A-k0(u+2)
    DO_PHASE(1, 0, { if (u + 2 < nt) STAGE_A(u + 2, 0, c); });
    __builtin_amdgcn_s_barrier();
    __builtin_amdgcn_sched_barrier(0);
    // ph3: A-k1 second half; stage B-k1(u+2)
    DO_PHASE(1, 1, { if (u + 2 < nt) STAGE_B(u + 2, 1, c); });
    if (u < nt - 1) {
      if (u + 1 == nt - 1) asm volatile("s_waitcnt vmcnt(0)" ::: "memory");
      else if (BN == 256)  asm volatile("s_waitcnt vmcnt(6)" ::: "memory");
      else                 asm volatile("s_waitcnt vmcnt(4)" ::: "memory");
      __builtin_amdgcn_sched_barrier(0);
      __builtin_amdgcn_s_barrier();
      __builtin_amdgcn_sched_barrier(0);
    }
  }
#undef DO_PHASE
#undef STAGE_A
#undef STAGE_B

  // epilogue: lane holds col fixed, rows lk*4 + r consecutive
#pragma unroll
  for (int mm = 0; mm < MF; ++mm) {
    const int row = bm0 + MROW + mm * 16 + (lk << 2);
#pragma unroll
    for (int nn = 0; nn < 4; ++nn) {
      const int col = bn0 + NCOL + nn * 16 + lr;
      f32x4 v = acc[mm][nn];
      if (EPI == 0) {
        const float bb = bias[col];
        if (col < 2 * CDIM) {
#pragma unroll
          for (int r = 0; r < 4; ++r)
            Cb[(size_t)(row + r) * ldc + col] = f2bf(v[r] + bb);
        } else {
          const int bq = row >> 11;
          const int j = row & (NTOK - 1);
          const int c2 = col - 2 * CDIM;
          uint2 pk;
          pk.x = (u32)f2bf(v[0] + bb) | ((u32)f2bf(v[1] + bb) << 16);
          pk.y = (u32)f2bf(v[2] + bb) | ((u32)f2bf(v[3] + bb) << 16);
          *(uint2*)&VT[((size_t)bq * CDIM + c2) * NTOK + j] = pk;
        }
      } else if (EPI == 1) {
        u16* Cp = Cb + (size_t)bz * sC;
#pragma unroll
        for (int r = 0; r < 4; ++r) {
          float sv = v[r] * SM_SCALE + pos[(size_t)(row + r) * NTOK + col];
          Cp[(size_t)(row + r) * ldc + col] = f2bf(sv);
        }
      } else {
        float* o = CT + (size_t)bz * sCT + (size_t)col * NTOK + row;
        *(f32x4*)o = v;
      }
    }
  }
}

// ---------------- row softmax, in place on bf16 [8192, 2048] ----------------
__global__ __launch_bounds__(256) void softmax_kernel(u16* __restrict__ S) {
  const size_t row = blockIdx.x;
  u16* Sr = S + row * NTOK;
  const int t = threadIdx.x;
  const int lane = t & 63, wv = t >> 6;
  uint4 d = ((const uint4*)Sr)[t];
  float v[8];
#pragma unroll
  for (int i = 0; i < 4; ++i) {
    u32 w = ((const u32*)&d)[i];
    v[2 * i]     = __uint_as_float(w << 16);
    v[2 * i + 1] = __uint_as_float(w & 0xffff0000u);
  }
  float mx = v[0];
#pragma unroll
  for (int i = 1; i < 8; ++i) mx = fmaxf(mx, v[i]);
#pragma unroll
  for (int o = 32; o > 0; o >>= 1) mx = fmaxf(mx, __shfl_xor(mx, o, 64));
  __shared__ float r1[4], r2[4];
  if (lane == 0) r1[wv] = mx;
  __syncthreads();
  mx = fmaxf(fmaxf(r1[0], r1[1]), fmaxf(r1[2], r1[3]));
  float e[8], s = 0.f;
#pragma unroll
  for (int i = 0; i < 8; ++i) { e[i] = __expf(v[i] - mx); s += e[i]; }
#pragma unroll
  for (int o = 32; o > 0; o >>= 1) s += __shfl_xor(s, o, 64);
  if (lane == 0) r2[wv] = s;
  __syncthreads();
  s = r2[0] + r2[1] + r2[2] + r2[3];
  const float inv = 1.f / s;
  uint4 o4;
#pragma unroll
  for (int i = 0; i < 4; ++i)
    ((u32*)&o4)[i] = (u32)f2bf(e[2 * i] * inv) | ((u32)f2bf(e[2 * i + 1] * inv) << 16);
  ((uint4*)Sr)[t] = o4;
}

extern "C" void kernel_launch(void* const* d_in, const int* in_sizes, int n_in,
                              void* d_out, int out_size, void* d_ws, size_t ws_size,
                              hipStream_t stream) {
  const float* x     = (const float*)d_in[0];
  const float* pos   = (const float*)d_in[1];
  const float* gamma = (const float*)d_in[2];
  const float* beta  = (const float*)d_in[3];
  const float* W     = (const float*)d_in[4];
  const float* bias  = (const float*)d_in[5];
  float* out = (float*)d_out;
  char* ws = (char*)d_ws;

  // workspace layout (118 MB total)
  u16* Wb  = (u16*)(ws);                  //  6 MB  [3072,1024] bf16
  u16* h   = (u16*)(ws + (6ll << 20));    // 16 MB  [8192,1024] bf16
  u16* qkv = (u16*)(ws + (22ll << 20));   // 48 MB  [8192,3072] bf16 (q,k cols used)
  u16* vT  = (u16*)(ws + (70ll << 20));   // 16 MB  [4][1024][2048] bf16
  u16* S   = (u16*)(ws + (86ll << 20));   // 32 MB  [4][2048][2048] bf16

  wconv_kernel<<<dim3((QKVD * CDIM / 8 + 255) / 256), 256, 0, stream>>>(W, Wb, QKVD * CDIM / 8);
  ln_kernel<<<dim3(BSZ * (NTOK / 32)), 512, 0, stream>>>(x, gamma, beta, h);

  // qkv = h @ W^T + b  (M=8192, N=3072, K=1024); v written transposed into vT
  gemmp_kernel<0, 256><<<dim3(MTOT / 256, QKVD / 256, 1), 512, 0, stream>>>(
      h, CDIM, 0, Wb, CDIM, 0, CDIM,
      bias, nullptr, qkv, QKVD, 0, vT, nullptr, 0);

  // S = q @ k^T * scale + position  (per batch M=N=2048, K=1024)
  gemmp_kernel<1, 256><<<dim3(NTOK / 256, NTOK / 256, BSZ), 512, 0, stream>>>(
      qkv, QKVD, (long)NTOK * QKVD, qkv + CDIM, QKVD, (long)NTOK * QKVD, CDIM,
      nullptr, pos, S, NTOK, (long)NTOK * NTOK, nullptr, nullptr, 0);

  softmax_kernel<<<dim3(MTOT), 256, 0, stream>>>(S);

  // out = P @ vT^T, written transposed to [B, C, N] f32
  gemmp_kernel<2, 128><<<dim3(NTOK / 256, CDIM / 128, BSZ), 512, 0, stream>>>(
      S, NTOK, (long)NTOK * NTOK, vT, NTOK, (long)CDIM * NTOK, NTOK,
      nullptr, nullptr, nullptr, 0, 0, nullptr, out, (long)CDIM * NTOK);
}

// Round 4
// 189.258 us; speedup vs baseline: 1.1886x; 1.0246x over previous
//
#include <hip/hip_runtime.h>
#include <stdint.h>

typedef unsigned short u16;
typedef unsigned int u32;

#define NTOK 2048
#define CDIM 1024
#define BSZ  4
#define MTOT (BSZ * NTOK)
#define QKVD 3072
#define SM_SCALE 0.02209708691207961f  // 1/sqrt(2048)

typedef __bf16 bf16x8 __attribute__((ext_vector_type(8)));
typedef float f32x4 __attribute__((ext_vector_type(4)));

__device__ __forceinline__ u16 f2bf(float f) {
  u32 u = __float_as_uint(f);
  u += 0x7fffu + ((u >> 16) & 1u);   // round-to-nearest-even
  return (u16)(u >> 16);
}

// ---------------- W fp32 -> bf16 convert ----------------
__global__ __launch_bounds__(256) void wconv_kernel(const float* __restrict__ W,
                                                    u16* __restrict__ Wb, int n8) {
  int i = blockIdx.x * 256 + threadIdx.x;
  if (i >= n8) return;
  const float4* p = (const float4*)W + (size_t)i * 2;
  float4 a = p[0], b = p[1];
  uint4 o;
  o.x = (u32)f2bf(a.x) | ((u32)f2bf(a.y) << 16);
  o.y = (u32)f2bf(a.z) | ((u32)f2bf(a.w) << 16);
  o.z = (u32)f2bf(b.x) | ((u32)f2bf(b.y) << 16);
  o.w = (u32)f2bf(b.z) | ((u32)f2bf(b.w) << 16);
  ((uint4*)Wb)[i] = o;
}

// ---------------- transpose + LayerNorm: x[B,C,N] -> h[B*N, C] bf16 ----------------
__global__ __launch_bounds__(512) void ln_kernel(const float* __restrict__ x,
                                                 const float* __restrict__ gamma,
                                                 const float* __restrict__ beta,
                                                 u16* __restrict__ h) {
  int blk = blockIdx.x;          // BSZ * (NTOK/32) = 256
  int b = blk >> 6;
  int n0 = (blk & 63) << 5;
  int t = threadIdx.x;
  int nl = t & 31;               // token lane
  int cp = t >> 5;               // 0..15 c-partition
  const float* xb = x + (size_t)b * CDIM * NTOK + n0 + nl;

  float s = 0.f, ss = 0.f;
  for (int k = 0; k < 64; ++k) {
    float v = xb[(size_t)(cp + (k << 4)) * NTOK];
    s += v; ss += v * v;
  }
  __shared__ float ps[16][32], pss[16][32];
  __shared__ float mean_s[32], rstd_s[32];
  ps[cp][nl] = s; pss[cp][nl] = ss;
  __syncthreads();
  if (t < 32) {
    float m = 0.f, q = 0.f;
#pragma unroll
    for (int p = 0; p < 16; ++p) { m += ps[p][t]; q += pss[p][t]; }
    float mu = m * (1.f / CDIM);
    float var = q * (1.f / CDIM) - mu * mu;
    mean_s[t] = mu;
    rstd_s[t] = rsqrtf(var + 1e-5f);
  }
  __syncthreads();
  float mu_n = mean_s[nl], rs_n = rstd_s[nl];

  __shared__ float tile[64][33];
  int tn = t >> 4, cl = t & 15;
  for (int kk = 0; kk < 16; ++kk) {
    __syncthreads();
#pragma unroll
    for (int i = 0; i < 4; ++i) {
      int c = (kk << 6) + (cp << 2) + i;
      float v = xb[(size_t)c * NTOK];
      tile[(cp << 2) + i][nl] = (v - mu_n) * rs_n * gamma[c] + beta[c];
    }
    __syncthreads();
    uint2 pk;
    pk.x = (u32)f2bf(tile[(cl << 2) + 0][tn]) | ((u32)f2bf(tile[(cl << 2) + 1][tn]) << 16);
    pk.y = (u32)f2bf(tile[(cl << 2) + 2][tn]) | ((u32)f2bf(tile[(cl << 2) + 3][tn]) << 16);
    *(uint2*)&h[(size_t)(b * NTOK + n0 + tn) * CDIM + (kk << 6) + (cl << 2)] = pk;
  }
}

// ---------------- 4-phase pipelined bf16 GEMM with register read-ahead ----------------
// C[row,col] = sum_k A[row,k]*B[col,k]. BM=256, BN=256|128, BK=64 (2 k-halves).
// Phase p: {stage freed region; ds_read frags for p+1 (alt reg set);
//           sched_barrier; [compiler counted lgkmcnt]; MFMA(p); s_barrier}
__device__ __forceinline__ void gld_lds16(const void* g, void* l) {
  __builtin_amdgcn_global_load_lds(
      (const __attribute__((address_space(1))) void*)g,
      (__attribute__((address_space(3))) void*)l, 16, 0, 0);
}

// stage a [128*NI rows][64B] k-half region; LDS linear, source slot-permuted
// LDS (row, s) holds global slot (s - (row>>1))&3  -> reader slot (lk+(row>>1))&3
template <int NI>
__device__ __forceinline__ void stage_reg(const char* g, long ld, char* lds, int t) {
  const long rbase = (long)(t >> 2) * ld + (((((t & 3) - (t >> 3)) & 3)) << 4);
#pragma unroll
  for (int i = 0; i < NI; ++i)
    gld_lds16(g + rbase + (long)i * 128 * ld,
              lds + ((t >> 6) << 10) + (i << 13));
}

template <int EPI, int BN>
__global__ __launch_bounds__(512, 2) void gemmp_kernel(
    const u16* __restrict__ A, int lda, long sA,
    const u16* __restrict__ B, int ldb, long sB, int K,
    const float* __restrict__ bias,   // EPI0
    const float* __restrict__ pos,    // EPI1
    u16* __restrict__ Cb, int ldc, long sC,  // EPI0/1 bf16 out
    u16* __restrict__ VT,             // EPI0: transposed v out [b][c][j]
    float* __restrict__ CT, long sCT) // EPI2: f32 out [col*NTOK + row]
{
  constexpr int GB  = (BN == 256) ? 2 : 1;   // gld per B-half per thread
  constexpr int MF  = (BN == 256) ? 8 : 4;   // m-frags per wave
  constexpr int MPP = MF / 2;                // m-frags per phase
  constexpr int ABUF = 65536;                // A: 2buf x 2half x 16KB
  constexpr int HB  = BN * 64;               // B half bytes
  __shared__ char smem[ABUF + 4 * HB];

  // chunked bijective XCD swizzle: xcd k owns m-chunk, intra m-fastest.
  const int GX = gridDim.x, GY = gridDim.y;
  const int hb = ((int)blockIdx.z * GY + blockIdx.y) * GX + blockIdx.x;
  const int MX = GX >> 3;
  const int k8 = hb & 7, j8 = hb >> 3;
  const int m = k8 * MX + (j8 % MX);
  const int rest = j8 / MX;
  const int n = rest % GY;
  const int bz = rest / GY;

  A += (size_t)bz * sA;
  B += (size_t)bz * sB;
  const int bm0 = m * 256;
  const int bn0 = n * BN;

  const int t = threadIdx.x;
  const int wave = t >> 6;
  const int wm = (BN == 256) ? (wave >> 2) : (wave >> 1);
  const int wn = (BN == 256) ? (wave & 3) : (wave & 1);
  const int MROW = wm * (MF * 16);
  const int NCOL = wn * 64;
  const int lr = t & 15, lk = (t & 63) >> 4;
  // per-lane fragment byte offset within a k-half region (bank-perfect)
  const int fragoff = lr * 64 + (((lk + (lr >> 1)) & 3) << 4);

  const long lda2 = (long)lda * 2, ldb2 = (long)ldb * 2;
  const char* Agb = (const char*)A + (size_t)bm0 * lda2;
  const char* Bgb = (const char*)B + (size_t)bn0 * ldb2;

#define STAGE_A(kt, h, cc) \
  stage_reg<2>(Agb + (long)(kt) * 128 + (h) * 64, lda2, smem + ((((cc) << 1) | (h)) << 14), t)
#define STAGE_B(kt, h, cc) \
  stage_reg<GB>(Bgb + (long)(kt) * 128 + (h) * 64, ldb2, smem + ABUF + ((((cc) << 1) | (h)) * HB), t)

  f32x4 acc[MF][4];
#pragma unroll
  for (int mm = 0; mm < MF; ++mm)
#pragma unroll
    for (int nn = 0; nn < 4; ++nn) acc[mm][nn] = (f32x4){0.f, 0.f, 0.f, 0.f};

  const int nt = K >> 6;   // >= 4
  // prologue: tiles 0 and 1, region order Bk0, Ak0, Bk1, Ak1
  STAGE_B(0, 0, 0); STAGE_A(0, 0, 0); STAGE_B(0, 1, 0); STAGE_A(0, 1, 0);
  STAGE_B(1, 0, 1); STAGE_A(1, 0, 1); STAGE_B(1, 1, 1); STAGE_A(1, 1, 1);
  if (BN == 256) asm volatile("s_waitcnt vmcnt(8)" ::: "memory");
  else           asm volatile("s_waitcnt vmcnt(6)" ::: "memory");
  __builtin_amdgcn_sched_barrier(0);
  __builtin_amdgcn_s_barrier();
  __builtin_amdgcn_sched_barrier(0);

  bf16x8 bv0[4], bv1[4], avA[MPP], avB[MPP];

#define READ_BV(dst, KS_)                                                      \
  _Pragma("unroll") for (int nn = 0; nn < 4; ++nn)                             \
    dst[nn] = *(const bf16x8*)(smem + ABUF + (((c << 1) | KS_) * HB) +         \
                               (NCOL + nn * 16) * 64 + fragoff);
#define READ_AV(dst, KS_, MP_)                                                 \
  _Pragma("unroll") for (int i = 0; i < MPP; ++i)                              \
    dst[i] = *(const bf16x8*)(smem + (((c << 1) | KS_) << 14) +                \
                              (MROW + (MP_ * MPP + i) * 16) * 64 + fragoff);
#define MFMA8(bvS, avS, MP_)                                                   \
  __builtin_amdgcn_s_setprio(1);                                              \
  _Pragma("unroll") for (int i = 0; i < MPP; ++i)                              \
    _Pragma("unroll") for (int nn = 0; nn < 4; ++nn)                           \
      acc[MP_ * MPP + i][nn] = __builtin_amdgcn_mfma_f32_16x16x32_bf16(        \
          avS[i], bvS[nn], acc[MP_ * MPP + i][nn], 0, 0, 0);                   \
  __builtin_amdgcn_s_setprio(0);
#define PHASE_CUT __builtin_amdgcn_sched_barrier(0)
#define BARRIER { PHASE_CUT; __builtin_amdgcn_s_barrier(); PHASE_CUT; }

  for (int u = 0; u < nt; ++u) {
    const int c = u & 1;
    // ph0: reads own frags (bv0, avA k0-MP0) + read-ahead avB (k0-MP1)
    if (u >= 1 && u + 1 < nt) STAGE_A(u + 1, 1, (u + 1) & 1);
    READ_BV(bv0, 0); READ_AV(avA, 0, 0); READ_AV(avB, 0, 1);
    PHASE_CUT;
    MFMA8(bv0, avA, 0);
    BARRIER;
    // ph1: read-ahead ph2 frags (bv1, avA k1-MP0); MFMA on bv0+avB
    if (u + 2 < nt) STAGE_B(u + 2, 0, c);
    READ_BV(bv1, 1); READ_AV(avA, 1, 0);
    PHASE_CUT;
    MFMA8(bv0, avB, 1);
    BARRIER;
    // ph2: read-ahead ph3 frags (avB k1-MP1); MFMA on bv1+avA
    if (u + 2 < nt) STAGE_A(u + 2, 0, c);
    READ_AV(avB, 1, 1);
    PHASE_CUT;
    MFMA8(bv1, avA, 0);
    BARRIER;
    // ph3: no read-ahead (tile-boundary); MFMA on bv1+avB
    if (u + 2 < nt) STAGE_B(u + 2, 1, c);
    PHASE_CUT;
    MFMA8(bv1, avB, 1);
    if (u < nt - 1) {
      if (u + 1 == nt - 1) asm volatile("s_waitcnt vmcnt(0)" ::: "memory");
      else if (BN == 256)  asm volatile("s_waitcnt vmcnt(6)" ::: "memory");
      else                 asm volatile("s_waitcnt vmcnt(4)" ::: "memory");
      BARRIER;
    }
  }
#undef READ_BV
#undef READ_AV
#undef MFMA8
#undef STAGE_A
#undef STAGE_B

  // epilogue: lane holds col fixed, rows lk*4 + r consecutive
#pragma unroll
  for (int mm = 0; mm < MF; ++mm) {
    const int row = bm0 + MROW + mm * 16 + (lk << 2);
#pragma unroll
    for (int nn = 0; nn < 4; ++nn) {
      const int col = bn0 + NCOL + nn * 16 + lr;
      f32x4 v = acc[mm][nn];
      if (EPI == 0) {
        const float bb = bias[col];
        if (col < 2 * CDIM) {
#pragma unroll
          for (int r = 0; r < 4; ++r)
            Cb[(size_t)(row + r) * ldc + col] = f2bf(v[r] + bb);
        } else {
          const int bq = row >> 11;
          const int j = row & (NTOK - 1);
          const int c2 = col - 2 * CDIM;
          uint2 pk;
          pk.x = (u32)f2bf(v[0] + bb) | ((u32)f2bf(v[1] + bb) << 16);
          pk.y = (u32)f2bf(v[2] + bb) | ((u32)f2bf(v[3] + bb) << 16);
          *(uint2*)&VT[((size_t)bq * CDIM + c2) * NTOK + j] = pk;
        }
      } else if (EPI == 1) {
        u16* Cp = Cb + (size_t)bz * sC;
#pragma unroll
        for (int r = 0; r < 4; ++r) {
          float sv = v[r] * SM_SCALE + pos[(size_t)(row + r) * NTOK + col];
          Cp[(size_t)(row + r) * ldc + col] = f2bf(sv);
        }
      } else {
        float* o = CT + (size_t)bz * sCT + (size_t)col * NTOK + row;
        *(f32x4*)o = v;
      }
    }
  }
}

// ---------------- row softmax, in place on bf16 [8192, 2048] ----------------
__global__ __launch_bounds__(256) void softmax_kernel(u16* __restrict__ S) {
  const size_t row = blockIdx.x;
  u16* Sr = S + row * NTOK;
  const int t = threadIdx.x;
  const int lane = t & 63, wv = t >> 6;
  uint4 d = ((const uint4*)Sr)[t];
  float v[8];
#pragma unroll
  for (int i = 0; i < 4; ++i) {
    u32 w = ((const u32*)&d)[i];
    v[2 * i]     = __uint_as_float(w << 16);
    v[2 * i + 1] = __uint_as_float(w & 0xffff0000u);
  }
  float mx = v[0];
#pragma unroll
  for (int i = 1; i < 8; ++i) mx = fmaxf(mx, v[i]);
#pragma unroll
  for (int o = 32; o > 0; o >>= 1) mx = fmaxf(mx, __shfl_xor(mx, o, 64));
  __shared__ float r1[4], r2[4];
  if (lane == 0) r1[wv] = mx;
  __syncthreads();
  mx = fmaxf(fmaxf(r1[0], r1[1]), fmaxf(r1[2], r1[3]));
  float e[8], s = 0.f;
#pragma unroll
  for (int i = 0; i < 8; ++i) { e[i] = __expf(v[i] - mx); s += e[i]; }
#pragma unroll
  for (int o = 32; o > 0; o >>= 1) s += __shfl_xor(s, o, 64);
  if (lane == 0) r2[wv] = s;
  __syncthreads();
  s = r2[0] + r2[1] + r2[2] + r2[3];
  const float inv = 1.f / s;
  uint4 o4;
#pragma unroll
  for (int i = 0; i < 4; ++i)
    ((u32*)&o4)[i] = (u32)f2bf(e[2 * i] * inv) | ((u32)f2bf(e[2 * i + 1] * inv) << 16);
  ((uint4*)Sr)[t] = o4;
}

extern "C" void kernel_launch(void* const* d_in, const int* in_sizes, int n_in,
                              void* d_out, int out_size, void* d_ws, size_t ws_size,
                              hipStream_t stream) {
  const float* x     = (const float*)d_in[0];
  const float* pos   = (const float*)d_in[1];
  const float* gamma = (const float*)d_in[2];
  const float* beta  = (const float*)d_in[3];
  const float* W     = (const float*)d_in[4];
  const float* bias  = (const float*)d_in[5];
  float* out = (float*)d_out;
  char* ws = (char*)d_ws;

  // workspace layout (118 MB total)
  u16* Wb  = (u16*)(ws);                  //  6 MB  [3072,1024] bf16
  u16* h   = (u16*)(ws + (6ll << 20));    // 16 MB  [8192,1024] bf16
  u16* qkv = (u16*)(ws + (22ll << 20));   // 48 MB  [8192,3072] bf16 (q,k cols used)
  u16* vT  = (u16*)(ws + (70ll << 20));   // 16 MB  [4][1024][2048] bf16
  u16* S   = (u16*)(ws + (86ll << 20));   // 32 MB  [4][2048][2048] bf16

  wconv_kernel<<<dim3((QKVD * CDIM / 8 + 255) / 256), 256, 0, stream>>>(W, Wb, QKVD * CDIM / 8);
  ln_kernel<<<dim3(BSZ * (NTOK / 32)), 512, 0, stream>>>(x, gamma, beta, h);

  // qkv = h @ W^T + b  (M=8192, N=3072, K=1024); v written transposed into vT
  gemmp_kernel<0, 256><<<dim3(MTOT / 256, QKVD / 256, 1), 512, 0, stream>>>(
      h, CDIM, 0, Wb, CDIM, 0, CDIM,
      bias, nullptr, qkv, QKVD, 0, vT, nullptr, 0);

  // S = q @ k^T * scale + position  (per batch M=N=2048, K=1024)
  gemmp_kernel<1, 256><<<dim3(NTOK / 256, NTOK / 256, BSZ), 512, 0, stream>>>(
      qkv, QKVD, (long)NTOK * QKVD, qkv + CDIM, QKVD, (long)NTOK * QKVD, CDIM,
      nullptr, pos, S, NTOK, (long)NTOK * NTOK, nullptr, nullptr, 0);

  softmax_kernel<<<dim3(MTOT), 256, 0, stream>>>(S);

  // out = P @ vT^T, written transposed to [B, C, N] f32
  gemmp_kernel<2, 128><<<dim3(NTOK / 256, CDIM / 128, BSZ), 512, 0, stream>>>(
      S, NTOK, (long)NTOK * NTOK, vT, NTOK, (long)CDIM * NTOK, NTOK,
      nullptr, nullptr, nullptr, 0, 0, nullptr, out, (long)CDIM * NTOK);
}

// Round 5
// 187.747 us; speedup vs baseline: 1.1982x; 1.0080x over previous
//
#include <hip/hip_runtime.h>
#include <stdint.h>

typedef unsigned short u16;
typedef unsigned int u32;

#define NTOK 2048
#define CDIM 1024
#define BSZ  4
#define MTOT (BSZ * NTOK)
#define QKVD 3072
#define SM_SCALE 0.02209708691207961f  // 1/sqrt(2048)

typedef __bf16 bf16x8 __attribute__((ext_vector_type(8)));
typedef float f32x4 __attribute__((ext_vector_type(4)));

__device__ __forceinline__ u16 f2bf(float f) {
  u32 u = __float_as_uint(f);
  u += 0x7fffu + ((u >> 16) & 1u);   // round-to-nearest-even
  return (u16)(u >> 16);
}

// ---------------- W fp32 -> bf16 convert ----------------
__global__ __launch_bounds__(256) void wconv_kernel(const float* __restrict__ W,
                                                    u16* __restrict__ Wb, int n8) {
  int i = blockIdx.x * 256 + threadIdx.x;
  if (i >= n8) return;
  const float4* p = (const float4*)W + (size_t)i * 2;
  float4 a = p[0], b = p[1];
  uint4 o;
  o.x = (u32)f2bf(a.x) | ((u32)f2bf(a.y) << 16);
  o.y = (u32)f2bf(a.z) | ((u32)f2bf(a.w) << 16);
  o.z = (u32)f2bf(b.x) | ((u32)f2bf(b.y) << 16);
  o.w = (u32)f2bf(b.z) | ((u32)f2bf(b.w) << 16);
  ((uint4*)Wb)[i] = o;
}

// ---------------- transpose + LayerNorm: x[B,C,N] -> h[B*N, C] bf16 ----------------
__global__ __launch_bounds__(512) void ln_kernel(const float* __restrict__ x,
                                                 const float* __restrict__ gamma,
                                                 const float* __restrict__ beta,
                                                 u16* __restrict__ h) {
  int blk = blockIdx.x;          // BSZ * (NTOK/32) = 256
  int b = blk >> 6;
  int n0 = (blk & 63) << 5;
  int t = threadIdx.x;
  int nl = t & 31;               // token lane
  int cp = t >> 5;               // 0..15 c-partition
  const float* xb = x + (size_t)b * CDIM * NTOK + n0 + nl;

  float s = 0.f, ss = 0.f;
  for (int k = 0; k < 64; ++k) {
    float v = xb[(size_t)(cp + (k << 4)) * NTOK];
    s += v; ss += v * v;
  }
  __shared__ float ps[16][32], pss[16][32];
  __shared__ float mean_s[32], rstd_s[32];
  ps[cp][nl] = s; pss[cp][nl] = ss;
  __syncthreads();
  if (t < 32) {
    float m = 0.f, q = 0.f;
#pragma unroll
    for (int p = 0; p < 16; ++p) { m += ps[p][t]; q += pss[p][t]; }
    float mu = m * (1.f / CDIM);
    float var = q * (1.f / CDIM) - mu * mu;
    mean_s[t] = mu;
    rstd_s[t] = rsqrtf(var + 1e-5f);
  }
  __syncthreads();
  float mu_n = mean_s[nl], rs_n = rstd_s[nl];

  __shared__ float tile[64][33];
  int tn = t >> 4, cl = t & 15;
  for (int kk = 0; kk < 16; ++kk) {
    __syncthreads();
#pragma unroll
    for (int i = 0; i < 4; ++i) {
      int c = (kk << 6) + (cp << 2) + i;
      float v = xb[(size_t)c * NTOK];
      tile[(cp << 2) + i][nl] = (v - mu_n) * rs_n * gamma[c] + beta[c];
    }
    __syncthreads();
    uint2 pk;
    pk.x = (u32)f2bf(tile[(cl << 2) + 0][tn]) | ((u32)f2bf(tile[(cl << 2) + 1][tn]) << 16);
    pk.y = (u32)f2bf(tile[(cl << 2) + 2][tn]) | ((u32)f2bf(tile[(cl << 2) + 3][tn]) << 16);
    *(uint2*)&h[(size_t)(b * NTOK + n0 + tn) * CDIM + (kk << 6) + (cl << 2)] = pk;
  }
}

// ---------------- 4-phase pipelined bf16 GEMM, counted waits, no setprio ----------------
// C[row,col] = sum_k A[row,k]*B[col,k]. BM=256, BN=256|128, BK=64 (2 k-halves).
// Phase p: {stage freed region; ds_read frags for p+1; lgkmcnt(N_ahead);
//           MFMA(p) overlapping the in-flight reads; s_barrier}
__device__ __forceinline__ void gld_lds16(const void* g, void* l) {
  __builtin_amdgcn_global_load_lds(
      (const __attribute__((address_space(1))) void*)g,
      (__attribute__((address_space(3))) void*)l, 16, 0, 0);
}

// stage a [128*NI rows][64B] k-half region; LDS linear, source slot-permuted
// LDS (row, s) holds global slot (s - (row>>1))&3  -> reader slot (lk+(row>>1))&3
template <int NI>
__device__ __forceinline__ void stage_reg(const char* g, long ld, char* lds, int t) {
  const long rbase = (long)(t >> 2) * ld + (((((t & 3) - (t >> 3)) & 3)) << 4);
#pragma unroll
  for (int i = 0; i < NI; ++i)
    gld_lds16(g + rbase + (long)i * 128 * ld,
              lds + ((t >> 6) << 10) + (i << 13));
}

template <int EPI, int BN>
__global__ __launch_bounds__(512, 2) void gemmp_kernel(
    const u16* __restrict__ A, int lda, long sA,
    const u16* __restrict__ B, int ldb, long sB, int K,
    const float* __restrict__ bias,   // EPI0
    const float* __restrict__ pos,    // EPI1
    u16* __restrict__ Cb, int ldc, long sC,  // EPI0/1 bf16 out
    u16* __restrict__ VT,             // EPI0: transposed v out [b][c][j]
    float* __restrict__ CT, long sCT) // EPI2: f32 out [col*NTOK + row]
{
  constexpr int GB  = (BN == 256) ? 2 : 1;   // gld per B-half per thread
  constexpr int MF  = (BN == 256) ? 8 : 4;   // m-frags per wave
  constexpr int MPP = MF / 2;                // m-frags per phase
  constexpr int ABUF = 65536;                // A: 2buf x 2half x 16KB
  constexpr int HB  = BN * 64;               // B half bytes
  __shared__ char smem[ABUF + 4 * HB];

  // chunked bijective XCD swizzle: xcd k owns m-chunk, intra m-fastest.
  const int GX = gridDim.x, GY = gridDim.y;
  const int hb = ((int)blockIdx.z * GY + blockIdx.y) * GX + blockIdx.x;
  const int MX = GX >> 3;
  const int k8 = hb & 7, j8 = hb >> 3;
  const int m = k8 * MX + (j8 % MX);
  const int rest = j8 / MX;
  const int n = rest % GY;
  const int bz = rest / GY;

  A += (size_t)bz * sA;
  B += (size_t)bz * sB;
  const int bm0 = m * 256;
  const int bn0 = n * BN;

  const int t = threadIdx.x;
  const int wave = t >> 6;
  const int wm = (BN == 256) ? (wave >> 2) : (wave >> 1);
  const int wn = (BN == 256) ? (wave & 3) : (wave & 1);
  const int MROW = wm * (MF * 16);
  const int NCOL = wn * 64;
  const int lr = t & 15, lk = (t & 63) >> 4;
  // per-lane fragment byte offset within a k-half region (bank-perfect)
  const int fragoff = lr * 64 + (((lk + (lr >> 1)) & 3) << 4);

  const long lda2 = (long)lda * 2, ldb2 = (long)ldb * 2;
  const char* Agb = (const char*)A + (size_t)bm0 * lda2;
  const char* Bgb = (const char*)B + (size_t)bn0 * ldb2;

#define STAGE_A(kt, h, cc) \
  stage_reg<2>(Agb + (long)(kt) * 128 + (h) * 64, lda2, smem + ((((cc) << 1) | (h)) << 14), t)
#define STAGE_B(kt, h, cc) \
  stage_reg<GB>(Bgb + (long)(kt) * 128 + (h) * 64, ldb2, smem + ABUF + ((((cc) << 1) | (h)) * HB), t)

  f32x4 acc[MF][4];
#pragma unroll
  for (int mm = 0; mm < MF; ++mm)
#pragma unroll
    for (int nn = 0; nn < 4; ++nn) acc[mm][nn] = (f32x4){0.f, 0.f, 0.f, 0.f};

  const int nt = K >> 6;   // >= 4
  // prologue: tiles 0 and 1, region order Bk0, Ak0, Bk1, Ak1
  STAGE_B(0, 0, 0); STAGE_A(0, 0, 0); STAGE_B(0, 1, 0); STAGE_A(0, 1, 0);
  STAGE_B(1, 0, 1); STAGE_A(1, 0, 1); STAGE_B(1, 1, 1); STAGE_A(1, 1, 1);
  if (BN == 256) asm volatile("s_waitcnt vmcnt(8)" ::: "memory");
  else           asm volatile("s_waitcnt vmcnt(6)" ::: "memory");
  __builtin_amdgcn_sched_barrier(0);
  __builtin_amdgcn_s_barrier();

  bf16x8 bv0[4], bv1[4], avA[MPP], avB[MPP];

#define READ_BV(dst, KS_)                                                      \
  _Pragma("unroll") for (int nn = 0; nn < 4; ++nn)                             \
    dst[nn] = *(const bf16x8*)(smem + ABUF + (((c << 1) | KS_) * HB) +         \
                               (NCOL + nn * 16) * 64 + fragoff);
#define READ_AV(dst, KS_, MP_)                                                 \
  _Pragma("unroll") for (int i = 0; i < MPP; ++i)                              \
    dst[i] = *(const bf16x8*)(smem + (((c << 1) | KS_) << 14) +                \
                              (MROW + (MP_ * MPP + i) * 16) * 64 + fragoff);
#define MFMA8(bvS, avS, MP_)                                                   \
  _Pragma("unroll") for (int i = 0; i < MPP; ++i)                              \
    _Pragma("unroll") for (int nn = 0; nn < 4; ++nn)                           \
      acc[MP_ * MPP + i][nn] = __builtin_amdgcn_mfma_f32_16x16x32_bf16(        \
          avS[i], bvS[nn], acc[MP_ * MPP + i][nn], 0, 0, 0);
#define LGKM_A  /* wait: own frags ready, MPP ahead-reads in flight */         \
  if (BN == 256) { asm volatile("s_waitcnt lgkmcnt(4)" ::: "memory"); }        \
  else           { asm volatile("s_waitcnt lgkmcnt(2)" ::: "memory"); }        \
  __builtin_amdgcn_sched_barrier(0);
#define LGKM_B  /* wait: prev ahead-reads ready, 4+MPP newer in flight */      \
  if (BN == 256) { asm volatile("s_waitcnt lgkmcnt(8)" ::: "memory"); }        \
  else           { asm volatile("s_waitcnt lgkmcnt(6)" ::: "memory"); }        \
  __builtin_amdgcn_sched_barrier(0);
#define LGKM_0                                                                 \
  asm volatile("s_waitcnt lgkmcnt(0)" ::: "memory");                           \
  __builtin_amdgcn_sched_barrier(0);

  for (int u = 0; u < nt; ++u) {
    const int c = u & 1;
    // ---- ph0: own reads (bv0, avA k0) + ahead avB(k0); MFMA k0-MP0 ----
    if (u >= 1 && u + 1 < nt) STAGE_A(u + 1, 1, (u + 1) & 1);
    READ_BV(bv0, 0); READ_AV(avA, 0, 0); READ_AV(avB, 0, 1);
    LGKM_A;
    MFMA8(bv0, avA, 0);
    __builtin_amdgcn_s_barrier();
    // ---- ph1: ahead bv1,avA(k1); MFMA k0-MP1 (avB in flight covered) ----
    if (u + 2 < nt) STAGE_B(u + 2, 0, c);
    READ_BV(bv1, 1); READ_AV(avA, 1, 0);
    LGKM_B;
    MFMA8(bv0, avB, 1);
    __builtin_amdgcn_s_barrier();
    // ---- ph2: ahead avB(k1); MFMA k1-MP0 ----
    if (u + 2 < nt) STAGE_A(u + 2, 0, c);
    READ_AV(avB, 1, 1);
    LGKM_A;
    MFMA8(bv1, avA, 0);
    __builtin_amdgcn_s_barrier();
    // ---- ph3: no reads; MFMA k1-MP1; tile-boundary vmcnt ----
    if (u + 2 < nt) STAGE_B(u + 2, 1, c);
    LGKM_0;
    MFMA8(bv1, avB, 1);
    if (u < nt - 1) {
      if (u + 1 == nt - 1) asm volatile("s_waitcnt vmcnt(0)" ::: "memory");
      else if (BN == 256)  asm volatile("s_waitcnt vmcnt(6)" ::: "memory");
      else                 asm volatile("s_waitcnt vmcnt(4)" ::: "memory");
      __builtin_amdgcn_sched_barrier(0);
      __builtin_amdgcn_s_barrier();
    }
  }
#undef READ_BV
#undef READ_AV
#undef MFMA8
#undef LGKM_A
#undef LGKM_B
#undef LGKM_0
#undef STAGE_A
#undef STAGE_B

  // epilogue: lane holds col fixed, rows lk*4 + r consecutive
#pragma unroll
  for (int mm = 0; mm < MF; ++mm) {
    const int row = bm0 + MROW + mm * 16 + (lk << 2);
#pragma unroll
    for (int nn = 0; nn < 4; ++nn) {
      const int col = bn0 + NCOL + nn * 16 + lr;
      f32x4 v = acc[mm][nn];
      if (EPI == 0) {
        const float bb = bias[col];
        if (col < 2 * CDIM) {
#pragma unroll
          for (int r = 0; r < 4; ++r)
            Cb[(size_t)(row + r) * ldc + col] = f2bf(v[r] + bb);
        } else {
          const int bq = row >> 11;
          const int j = row & (NTOK - 1);
          const int c2 = col - 2 * CDIM;
          uint2 pk;
          pk.x = (u32)f2bf(v[0] + bb) | ((u32)f2bf(v[1] + bb) << 16);
          pk.y = (u32)f2bf(v[2] + bb) | ((u32)f2bf(v[3] + bb) << 16);
          *(uint2*)&VT[((size_t)bq * CDIM + c2) * NTOK + j] = pk;
        }
      } else if (EPI == 1) {
        u16* Cp = Cb + (size_t)bz * sC;
#pragma unroll
        for (int r = 0; r < 4; ++r) {
          float sv = v[r] * SM_SCALE + pos[(size_t)(row + r) * NTOK + col];
          Cp[(size_t)(row + r) * ldc + col] = f2bf(sv);
        }
      } else {
        float* o = CT + (size_t)bz * sCT + (size_t)col * NTOK + row;
        *(f32x4*)o = v;
      }
    }
  }
}

// ---------------- row softmax, in place on bf16 [8192, 2048] ----------------
__global__ __launch_bounds__(256) void softmax_kernel(u16* __restrict__ S) {
  const size_t row = blockIdx.x;
  u16* Sr = S + row * NTOK;
  const int t = threadIdx.x;
  const int lane = t & 63, wv = t >> 6;
  uint4 d = ((const uint4*)Sr)[t];
  float v[8];
#pragma unroll
  for (int i = 0; i < 4; ++i) {
    u32 w = ((const u32*)&d)[i];
    v[2 * i]     = __uint_as_float(w << 16);
    v[2 * i + 1] = __uint_as_float(w & 0xffff0000u);
  }
  float mx = v[0];
#pragma unroll
  for (int i = 1; i < 8; ++i) mx = fmaxf(mx, v[i]);
#pragma unroll
  for (int o = 32; o > 0; o >>= 1) mx = fmaxf(mx, __shfl_xor(mx, o, 64));
  __shared__ float r1[4], r2[4];
  if (lane == 0) r1[wv] = mx;
  __syncthreads();
  mx = fmaxf(fmaxf(r1[0], r1[1]), fmaxf(r1[2], r1[3]));
  float e[8], s = 0.f;
#pragma unroll
  for (int i = 0; i < 8; ++i) { e[i] = __expf(v[i] - mx); s += e[i]; }
#pragma unroll
  for (int o = 32; o > 0; o >>= 1) s += __shfl_xor(s, o, 64);
  if (lane == 0) r2[wv] = s;
  __syncthreads();
  s = r2[0] + r2[1] + r2[2] + r2[3];
  const float inv = 1.f / s;
  uint4 o4;
#pragma unroll
  for (int i = 0; i < 4; ++i)
    ((u32*)&o4)[i] = (u32)f2bf(e[2 * i] * inv) | ((u32)f2bf(e[2 * i + 1] * inv) << 16);
  ((uint4*)Sr)[t] = o4;
}

extern "C" void kernel_launch(void* const* d_in, const int* in_sizes, int n_in,
                              void* d_out, int out_size, void* d_ws, size_t ws_size,
                              hipStream_t stream) {
  const float* x     = (const float*)d_in[0];
  const float* pos   = (const float*)d_in[1];
  const float* gamma = (const float*)d_in[2];
  const float* beta  = (const float*)d_in[3];
  const float* W     = (const float*)d_in[4];
  const float* bias  = (const float*)d_in[5];
  float* out = (float*)d_out;
  char* ws = (char*)d_ws;

  // workspace layout (118 MB total)
  u16* Wb  = (u16*)(ws);                  //  6 MB  [3072,1024] bf16
  u16* h   = (u16*)(ws + (6ll << 20));    // 16 MB  [8192,1024] bf16
  u16* qkv = (u16*)(ws + (22ll << 20));   // 48 MB  [8192,3072] bf16 (q,k cols used)
  u16* vT  = (u16*)(ws + (70ll << 20));   // 16 MB  [4][1024][2048] bf16
  u16* S   = (u16*)(ws + (86ll << 20));   // 32 MB  [4][2048][2048] bf16

  wconv_kernel<<<dim3((QKVD * CDIM / 8 + 255) / 256), 256, 0, stream>>>(W, Wb, QKVD * CDIM / 8);
  ln_kernel<<<dim3(BSZ * (NTOK / 32)), 512, 0, stream>>>(x, gamma, beta, h);

  // qkv = h @ W^T + b  (M=8192, N=3072, K=1024); v written transposed into vT
  gemmp_kernel<0, 256><<<dim3(MTOT / 256, QKVD / 256, 1), 512, 0, stream>>>(
      h, CDIM, 0, Wb, CDIM, 0, CDIM,
      bias, nullptr, qkv, QKVD, 0, vT, nullptr, 0);

  // S = q @ k^T * scale + position  (per batch M=N=2048, K=1024)
  gemmp_kernel<1, 256><<<dim3(NTOK / 256, NTOK / 256, BSZ), 512, 0, stream>>>(
      qkv, QKVD, (long)NTOK * QKVD, qkv + CDIM, QKVD, (long)NTOK * QKVD, CDIM,
      nullptr, pos, S, NTOK, (long)NTOK * NTOK, nullptr, nullptr, 0);

  softmax_kernel<<<dim3(MTOT), 256, 0, stream>>>(S);

  // out = P @ vT^T, written transposed to [B, C, N] f32
  gemmp_kernel<2, 128><<<dim3(NTOK / 256, CDIM / 128, BSZ), 512, 0, stream>>>(
      S, NTOK, (long)NTOK * NTOK, vT, NTOK, (long)CDIM * NTOK, NTOK,
      nullptr, nullptr, nullptr, 0, 0, nullptr, out, (long)CDIM * NTOK);
}

// Round 6
// 182.593 us; speedup vs baseline: 1.2320x; 1.0282x over previous
//
#include <hip/hip_runtime.h>
#include <stdint.h>

typedef unsigned short u16;
typedef unsigned int u32;

#define NTOK 2048
#define CDIM 1024
#define BSZ  4
#define MTOT (BSZ * NTOK)
#define QKVD 3072
#define SM_SCALE 0.02209708691207961f  // 1/sqrt(2048)

typedef __bf16 bf16x8 __attribute__((ext_vector_type(8)));
typedef float f32x4 __attribute__((ext_vector_type(4)));

__device__ __forceinline__ u16 f2bf(float f) {
  u32 u = __float_as_uint(f);
  u += 0x7fffu + ((u >> 16) & 1u);   // round-to-nearest-even
  return (u16)(u >> 16);
}

// ---------------- W fp32 -> bf16 convert ----------------
__global__ __launch_bounds__(256) void wconv_kernel(const float* __restrict__ W,
                                                    u16* __restrict__ Wb, int n8) {
  int i = blockIdx.x * 256 + threadIdx.x;
  if (i >= n8) return;
  const float4* p = (const float4*)W + (size_t)i * 2;
  float4 a = p[0], b = p[1];
  uint4 o;
  o.x = (u32)f2bf(a.x) | ((u32)f2bf(a.y) << 16);
  o.y = (u32)f2bf(a.z) | ((u32)f2bf(a.w) << 16);
  o.z = (u32)f2bf(b.x) | ((u32)f2bf(b.y) << 16);
  o.w = (u32)f2bf(b.z) | ((u32)f2bf(b.w) << 16);
  ((uint4*)Wb)[i] = o;
}

// ---------------- one-pass transpose + LayerNorm: x[B,C,N] -> h[B*N, C] bf16 ----
// thread (nl, cp) holds its 64-element c-slice of token n0+nl in registers.
__global__ __launch_bounds__(512) void ln_kernel(const float* __restrict__ x,
                                                 const float* __restrict__ gamma,
                                                 const float* __restrict__ beta,
                                                 u16* __restrict__ h) {
  int blk = blockIdx.x;          // BSZ * (NTOK/32) = 256
  int b = blk >> 6;
  int n0 = (blk & 63) << 5;
  int t = threadIdx.x;
  int nl = t & 31;               // token lane
  int cp = t >> 5;               // 0..15 c-partition
  const float* xb = x + (size_t)b * CDIM * NTOK + n0 + nl;

  float v[64];
  float s = 0.f, ss = 0.f;
#pragma unroll
  for (int k = 0; k < 64; ++k) {
    v[k] = xb[(size_t)(cp + (k << 4)) * NTOK];
    s += v[k]; ss += v[k] * v[k];
  }
  __shared__ float ps[16][32], pss[16][32];
  __shared__ float mean_s[32], rstd_s[32];
  ps[cp][nl] = s; pss[cp][nl] = ss;
  __syncthreads();
  if (t < 32) {
    float m = 0.f, q = 0.f;
#pragma unroll
    for (int p = 0; p < 16; ++p) { m += ps[p][t]; q += pss[p][t]; }
    float mu = m * (1.f / CDIM);
    float var = q * (1.f / CDIM) - mu * mu;
    mean_s[t] = mu;
    rstd_s[t] = rsqrtf(var + 1e-5f);
  }
  __syncthreads();
  float mu_n = mean_s[nl], rs_n = rstd_s[nl];

  __shared__ float tile[64][33];
  int tn = t >> 4, cl = t & 15;
#pragma unroll
  for (int kk = 0; kk < 16; ++kk) {
    __syncthreads();
#pragma unroll
    for (int i = 0; i < 4; ++i) {
      int c = (kk << 6) + (i << 4) + cp;     // = kk*64 + i*16 + cp
      tile[(i << 4) + cp][nl] = (v[(kk << 2) + i] - mu_n) * rs_n * gamma[c] + beta[c];
    }
    __syncthreads();
    uint2 pk;
    pk.x = (u32)f2bf(tile[(cl << 2) + 0][tn]) | ((u32)f2bf(tile[(cl << 2) + 1][tn]) << 16);
    pk.y = (u32)f2bf(tile[(cl << 2) + 2][tn]) | ((u32)f2bf(tile[(cl << 2) + 3][tn]) << 16);
    *(uint2*)&h[(size_t)(b * NTOK + n0 + tn) * CDIM + (kk << 6) + (cl << 2)] = pk;
  }
}

// ---------------- m97-style bf16 GEMM, B^T layout, 128x128 tile ----------------
// C[row,col] = sum_k A[row,k]*B[col,k]. BK=64, 4 waves (2Mx2N), 32KB LDS,
// single-buffered stage->sync->compute; 3 blocks/CU provide cross-block overlap.
__device__ __forceinline__ void gld_lds16(const void* g, void* l) {
  __builtin_amdgcn_global_load_lds(
      (const __attribute__((address_space(1))) void*)g,
      (__attribute__((address_space(3))) void*)l, 16, 0, 0);
}

// stage a [128 rows][64B] k-half region with 256 threads (2 gld/thread).
// LDS dest linear (wave-uniform + lane*16); global source slot-permuted so
// LDS (row, s) holds global slot (s - (row>>1))&3  -> conflict-free reads.
__device__ __forceinline__ void stage128(const char* g, long ld, char* lds, int t) {
  const long rb = (long)(t >> 2) * ld + ((((t & 3) - (t >> 3)) & 3) << 4);
#pragma unroll
  for (int i = 0; i < 2; ++i)
    gld_lds16(g + rb + (long)(i * 64) * ld,
              lds + ((t >> 6) << 10) + (i << 12));
}

template <int EPI>
__global__ __launch_bounds__(256, 3) void gemm_kernel(
    const u16* __restrict__ A, int lda, long sA,
    const u16* __restrict__ B, int ldb, long sB, int K,
    const float* __restrict__ bias,   // EPI0
    const float* __restrict__ pos,    // EPI1
    u16* __restrict__ Cb, int ldc, long sC,  // EPI0/1 bf16 out
    u16* __restrict__ VT,             // EPI0: transposed v out [b][c][j]
    float* __restrict__ CT, long sCT) // EPI2: f32 out [col*NTOK + row]
{
  // LDS: A kh0 @0, A kh1 @8K, B kh0 @16K, B kh1 @24K  (32KB total)
  __shared__ char smem[32768];

  // chunked bijective XCD swizzle: xcd k owns m-chunk, intra m-fastest.
  const int GX = gridDim.x, GY = gridDim.y;
  const int hb = ((int)blockIdx.z * GY + blockIdx.y) * GX + blockIdx.x;
  const int MX = GX >> 3;
  const int k8 = hb & 7, j8 = hb >> 3;
  const int m = k8 * MX + (j8 % MX);
  const int rest = j8 / MX;
  const int n = rest % GY;
  const int bz = rest / GY;

  A += (size_t)bz * sA;
  B += (size_t)bz * sB;
  const int bm0 = m * 128;
  const int bn0 = n * 128;

  const int t = threadIdx.x;
  const int wave = t >> 6;
  const int wm = wave >> 1, wn = wave & 1;
  const int MROW = wm * 64, NCOL = wn * 64;
  const int lr = t & 15, lk = (t & 63) >> 4;
  // per-lane fragment byte offset within a k-half region (bank-perfect)
  const int fragoff = lr * 64 + (((lk + (lr >> 1)) & 3) << 4);

  const long lda2 = (long)lda * 2, ldb2 = (long)ldb * 2;
  const char* Agb = (const char*)A + (size_t)bm0 * lda2;
  const char* Bgb = (const char*)B + (size_t)bn0 * ldb2;

  f32x4 acc[4][4];
#pragma unroll
  for (int mm = 0; mm < 4; ++mm)
#pragma unroll
    for (int nn = 0; nn < 4; ++nn) acc[mm][nn] = (f32x4){0.f, 0.f, 0.f, 0.f};

  const int nt = K >> 6;
  for (int kt = 0; kt < nt; ++kt) {
    __syncthreads();   // all prior LDS reads complete everywhere
    const long kb = (long)kt * 128;
    stage128(Agb + kb,      lda2, smem,          t);
    stage128(Agb + kb + 64, lda2, smem + 8192,   t);
    stage128(Bgb + kb,      ldb2, smem + 16384,  t);
    stage128(Bgb + kb + 64, ldb2, smem + 24576,  t);
    __syncthreads();   // implies vmcnt(0): staged data landed

#pragma unroll
    for (int ks = 0; ks < 2; ++ks) {
      const char* Ab = smem + ks * 8192;
      const char* Bb = smem + 16384 + ks * 8192;
      bf16x8 av[4], bv[4];
#pragma unroll
      for (int i = 0; i < 4; ++i)
        av[i] = *(const bf16x8*)(Ab + (MROW + i * 16) * 64 + fragoff);
#pragma unroll
      for (int i = 0; i < 4; ++i)
        bv[i] = *(const bf16x8*)(Bb + (NCOL + i * 16) * 64 + fragoff);
#pragma unroll
      for (int mm = 0; mm < 4; ++mm)
#pragma unroll
        for (int nn = 0; nn < 4; ++nn)
          acc[mm][nn] = __builtin_amdgcn_mfma_f32_16x16x32_bf16(av[mm], bv[nn],
                                                                acc[mm][nn], 0, 0, 0);
    }
  }

  // epilogue: lane holds col fixed, rows lk*4 + r consecutive
#pragma unroll
  for (int mm = 0; mm < 4; ++mm) {
    const int row = bm0 + MROW + mm * 16 + (lk << 2);
#pragma unroll
    for (int nn = 0; nn < 4; ++nn) {
      const int col = bn0 + NCOL + nn * 16 + lr;
      f32x4 v = acc[mm][nn];
      if (EPI == 0) {
        const float bb = bias[col];
        if (col < 2 * CDIM) {
#pragma unroll
          for (int r = 0; r < 4; ++r)
            Cb[(size_t)(row + r) * ldc + col] = f2bf(v[r] + bb);
        } else {
          const int bq = row >> 11;
          const int j = row & (NTOK - 1);
          const int c2 = col - 2 * CDIM;
          uint2 pk;
          pk.x = (u32)f2bf(v[0] + bb) | ((u32)f2bf(v[1] + bb) << 16);
          pk.y = (u32)f2bf(v[2] + bb) | ((u32)f2bf(v[3] + bb) << 16);
          *(uint2*)&VT[((size_t)bq * CDIM + c2) * NTOK + j] = pk;
        }
      } else if (EPI == 1) {
        u16* Cp = Cb + (size_t)bz * sC;
#pragma unroll
        for (int r = 0; r < 4; ++r) {
          float sv = v[r] * SM_SCALE + pos[(size_t)(row + r) * NTOK + col];
          Cp[(size_t)(row + r) * ldc + col] = f2bf(sv);
        }
      } else {
        float* o = CT + (size_t)bz * sCT + (size_t)col * NTOK + row;
        *(f32x4*)o = v;
      }
    }
  }
}

// ---------------- row softmax, in place on bf16 [8192, 2048] ----------------
__global__ __launch_bounds__(256) void softmax_kernel(u16* __restrict__ S) {
  const size_t row = blockIdx.x;
  u16* Sr = S + row * NTOK;
  const int t = threadIdx.x;
  const int lane = t & 63, wv = t >> 6;
  uint4 d = ((const uint4*)Sr)[t];
  float v[8];
#pragma unroll
  for (int i = 0; i < 4; ++i) {
    u32 w = ((const u32*)&d)[i];
    v[2 * i]     = __uint_as_float(w << 16);
    v[2 * i + 1] = __uint_as_float(w & 0xffff0000u);
  }
  float mx = v[0];
#pragma unroll
  for (int i = 1; i < 8; ++i) mx = fmaxf(mx, v[i]);
#pragma unroll
  for (int o = 32; o > 0; o >>= 1) mx = fmaxf(mx, __shfl_xor(mx, o, 64));
  __shared__ float r1[4], r2[4];
  if (lane == 0) r1[wv] = mx;
  __syncthreads();
  mx = fmaxf(fmaxf(r1[0], r1[1]), fmaxf(r1[2], r1[3]));
  float e[8], s = 0.f;
#pragma unroll
  for (int i = 0; i < 8; ++i) { e[i] = __expf(v[i] - mx); s += e[i]; }
#pragma unroll
  for (int o = 32; o > 0; o >>= 1) s += __shfl_xor(s, o, 64);
  if (lane == 0) r2[wv] = s;
  __syncthreads();
  s = r2[0] + r2[1] + r2[2] + r2[3];
  const float inv = 1.f / s;
  uint4 o4;
#pragma unroll
  for (int i = 0; i < 4; ++i)
    ((u32*)&o4)[i] = (u32)f2bf(e[2 * i] * inv) | ((u32)f2bf(e[2 * i + 1] * inv) << 16);
  ((uint4*)Sr)[t] = o4;
}

extern "C" void kernel_launch(void* const* d_in, const int* in_sizes, int n_in,
                              void* d_out, int out_size, void* d_ws, size_t ws_size,
                              hipStream_t stream) {
  const float* x     = (const float*)d_in[0];
  const float* pos   = (const float*)d_in[1];
  const float* gamma = (const float*)d_in[2];
  const float* beta  = (const float*)d_in[3];
  const float* W     = (const float*)d_in[4];
  const float* bias  = (const float*)d_in[5];
  float* out = (float*)d_out;
  char* ws = (char*)d_ws;

  // workspace layout (118 MB total)
  u16* Wb  = (u16*)(ws);                  //  6 MB  [3072,1024] bf16
  u16* h   = (u16*)(ws + (6ll << 20));    // 16 MB  [8192,1024] bf16
  u16* qkv = (u16*)(ws + (22ll << 20));   // 48 MB  [8192,3072] bf16 (q,k cols used)
  u16* vT  = (u16*)(ws + (70ll << 20));   // 16 MB  [4][1024][2048] bf16
  u16* S   = (u16*)(ws + (86ll << 20));   // 32 MB  [4][2048][2048] bf16

  wconv_kernel<<<dim3((QKVD * CDIM / 8 + 255) / 256), 256, 0, stream>>>(W, Wb, QKVD * CDIM / 8);
  ln_kernel<<<dim3(BSZ * (NTOK / 32)), 512, 0, stream>>>(x, gamma, beta, h);

  // qkv = h @ W^T + b  (M=8192, N=3072, K=1024); v written transposed into vT
  gemm_kernel<0><<<dim3(MTOT / 128, QKVD / 128, 1), 256, 0, stream>>>(
      h, CDIM, 0, Wb, CDIM, 0, CDIM,
      bias, nullptr, qkv, QKVD, 0, vT, nullptr, 0);

  // S = q @ k^T * scale + position  (per batch M=N=2048, K=1024)
  gemm_kernel<1><<<dim3(NTOK / 128, NTOK / 128, BSZ), 256, 0, stream>>>(
      qkv, QKVD, (long)NTOK * QKVD, qkv + CDIM, QKVD, (long)NTOK * QKVD, CDIM,
      nullptr, pos, S, NTOK, (long)NTOK * NTOK, nullptr, nullptr, 0);

  softmax_kernel<<<dim3(MTOT), 256, 0, stream>>>(S);

  // out = P @ vT^T, written transposed to [B, C, N] f32
  gemm_kernel<2><<<dim3(NTOK / 128, CDIM / 128, BSZ), 256, 0, stream>>>(
      S, NTOK, (long)NTOK * NTOK, vT, NTOK, (long)CDIM * NTOK, NTOK,
      nullptr, nullptr, nullptr, 0, 0, nullptr, out, (long)CDIM * NTOK);
}

// Round 7
// 174.577 us; speedup vs baseline: 1.2886x; 1.0459x over previous
//
#include <hip/hip_runtime.h>
#include <stdint.h>

typedef unsigned short u16;
typedef unsigned int u32;

#define NTOK 2048
#define CDIM 1024
#define BSZ  4
#define MTOT (BSZ * NTOK)
#define QKVD 3072
#define SM_SCALE 0.02209708691207961f  // 1/sqrt(2048)

typedef __bf16 bf16x8 __attribute__((ext_vector_type(8)));
typedef float f32x4 __attribute__((ext_vector_type(4)));

__device__ __forceinline__ u16 f2bf(float f) {
  u32 u = __float_as_uint(f);
  u += 0x7fffu + ((u >> 16) & 1u);   // round-to-nearest-even
  return (u16)(u >> 16);
}

// ---------------- W fp32 -> bf16 convert ----------------
__global__ __launch_bounds__(256) void wconv_kernel(const float* __restrict__ W,
                                                    u16* __restrict__ Wb, int n8) {
  int i = blockIdx.x * 256 + threadIdx.x;
  if (i >= n8) return;
  const float4* p = (const float4*)W + (size_t)i * 2;
  float4 a = p[0], b = p[1];
  uint4 o;
  o.x = (u32)f2bf(a.x) | ((u32)f2bf(a.y) << 16);
  o.y = (u32)f2bf(a.z) | ((u32)f2bf(a.w) << 16);
  o.z = (u32)f2bf(b.x) | ((u32)f2bf(b.y) << 16);
  o.w = (u32)f2bf(b.z) | ((u32)f2bf(b.w) << 16);
  ((uint4*)Wb)[i] = o;
}

// ---------------- zero rowsum buffer ----------------
__global__ __launch_bounds__(256) void zero_kernel(float* __restrict__ p, int n) {
  int i = blockIdx.x * 256 + threadIdx.x;
  if (i < n) p[i] = 0.f;
}

// ---------------- one-pass transpose + LayerNorm: x[B,C,N] -> h[B*N, C] bf16 ----
__global__ __launch_bounds__(512) void ln_kernel(const float* __restrict__ x,
                                                 const float* __restrict__ gamma,
                                                 const float* __restrict__ beta,
                                                 u16* __restrict__ h) {
  int blk = blockIdx.x;          // BSZ * (NTOK/32) = 256
  int b = blk >> 6;
  int n0 = (blk & 63) << 5;
  int t = threadIdx.x;
  int nl = t & 31;               // token lane
  int cp = t >> 5;               // 0..15 c-partition
  const float* xb = x + (size_t)b * CDIM * NTOK + n0 + nl;

  float v[64];
  float s = 0.f, ss = 0.f;
#pragma unroll
  for (int k = 0; k < 64; ++k) {
    v[k] = xb[(size_t)(cp + (k << 4)) * NTOK];
    s += v[k]; ss += v[k] * v[k];
  }
  __shared__ float ps[16][32], pss[16][32];
  __shared__ float mean_s[32], rstd_s[32];
  ps[cp][nl] = s; pss[cp][nl] = ss;
  __syncthreads();
  if (t < 32) {
    float m = 0.f, q = 0.f;
#pragma unroll
    for (int p = 0; p < 16; ++p) { m += ps[p][t]; q += pss[p][t]; }
    float mu = m * (1.f / CDIM);
    float var = q * (1.f / CDIM) - mu * mu;
    mean_s[t] = mu;
    rstd_s[t] = rsqrtf(var + 1e-5f);
  }
  __syncthreads();
  float mu_n = mean_s[nl], rs_n = rstd_s[nl];

  __shared__ float tile[64][33];
  int tn = t >> 4, cl = t & 15;
#pragma unroll
  for (int kk = 0; kk < 16; ++kk) {
    __syncthreads();
#pragma unroll
    for (int i = 0; i < 4; ++i) {
      int c = (kk << 6) + (i << 4) + cp;     // = kk*64 + i*16 + cp
      tile[(i << 4) + cp][nl] = (v[(kk << 2) + i] - mu_n) * rs_n * gamma[c] + beta[c];
    }
    __syncthreads();
    uint2 pk;
    pk.x = (u32)f2bf(tile[(cl << 2) + 0][tn]) | ((u32)f2bf(tile[(cl << 2) + 1][tn]) << 16);
    pk.y = (u32)f2bf(tile[(cl << 2) + 2][tn]) | ((u32)f2bf(tile[(cl << 2) + 3][tn]) << 16);
    *(uint2*)&h[(size_t)(b * NTOK + n0 + tn) * CDIM + (kk << 6) + (cl << 2)] = pk;
  }
}

// ---------------- m97-style bf16 GEMM, B^T layout, 128x128 tile ----------------
// C[row,col] = sum_k A[row,k]*B[col,k]. BK=64, 4 waves (2Mx2N), 32KB LDS,
// single-buffered stage->sync->compute; 3 blocks/CU provide cross-block overlap.
// EPI1 fuses unnormalized softmax (exp + row-sum atomics); EPI2 divides by sums.
__device__ __forceinline__ void gld_lds16(const void* g, void* l) {
  __builtin_amdgcn_global_load_lds(
      (const __attribute__((address_space(1))) void*)g,
      (__attribute__((address_space(3))) void*)l, 16, 0, 0);
}

// stage a [128 rows][64B] k-half region with 256 threads (2 gld/thread).
// LDS dest linear (wave-uniform + lane*16); global source slot-permuted so
// LDS (row, s) holds global slot (s - (row>>1))&3  -> conflict-free reads.
__device__ __forceinline__ void stage128(const char* g, long ld, char* lds, int t) {
  const long rb = (long)(t >> 2) * ld + ((((t & 3) - (t >> 3)) & 3) << 4);
#pragma unroll
  for (int i = 0; i < 2; ++i)
    gld_lds16(g + rb + (long)(i * 64) * ld,
              lds + ((t >> 6) << 10) + (i << 12));
}

template <int EPI>
__global__ __launch_bounds__(256, 3) void gemm_kernel(
    const u16* __restrict__ A, int lda, long sA,
    const u16* __restrict__ B, int ldb, long sB, int K,
    const float* __restrict__ bias,   // EPI0
    const float* __restrict__ pos,    // EPI1
    u16* __restrict__ Cb, int ldc, long sC,  // EPI0/1 bf16 out
    u16* __restrict__ VT,             // EPI0: transposed v out [b][c][j]
    float* __restrict__ CT, long sCT, // EPI2: f32 out [col*NTOK + row]
    float* __restrict__ RS)           // EPI1: atomic row sums; EPI2: read
{
  // LDS: A kh0 @0, A kh1 @8K, B kh0 @16K, B kh1 @24K  (32KB total)
  __shared__ char smem[32768];

  // chunked bijective XCD swizzle: xcd k owns m-chunk, intra m-fastest.
  const int GX = gridDim.x, GY = gridDim.y;
  const int hb = ((int)blockIdx.z * GY + blockIdx.y) * GX + blockIdx.x;
  const int MX = GX >> 3;
  const int k8 = hb & 7, j8 = hb >> 3;
  const int m = k8 * MX + (j8 % MX);
  const int rest = j8 / MX;
  const int n = rest % GY;
  const int bz = rest / GY;

  A += (size_t)bz * sA;
  B += (size_t)bz * sB;
  const int bm0 = m * 128;
  const int bn0 = n * 128;

  const int t = threadIdx.x;
  const int wave = t >> 6;
  const int wm = wave >> 1, wn = wave & 1;
  const int MROW = wm * 64, NCOL = wn * 64;
  const int lr = t & 15, lk = (t & 63) >> 4;
  // per-lane fragment byte offset within a k-half region (bank-perfect)
  const int fragoff = lr * 64 + (((lk + (lr >> 1)) & 3) << 4);

  const long lda2 = (long)lda * 2, ldb2 = (long)ldb * 2;
  const char* Agb = (const char*)A + (size_t)bm0 * lda2;
  const char* Bgb = (const char*)B + (size_t)bn0 * ldb2;

  f32x4 acc[4][4];
#pragma unroll
  for (int mm = 0; mm < 4; ++mm)
#pragma unroll
    for (int nn = 0; nn < 4; ++nn) acc[mm][nn] = (f32x4){0.f, 0.f, 0.f, 0.f};

  const int nt = K >> 6;
  for (int kt = 0; kt < nt; ++kt) {
    __syncthreads();   // all prior LDS reads complete everywhere
    const long kb = (long)kt * 128;
    stage128(Agb + kb,      lda2, smem,          t);
    stage128(Agb + kb + 64, lda2, smem + 8192,   t);
    stage128(Bgb + kb,      ldb2, smem + 16384,  t);
    stage128(Bgb + kb + 64, ldb2, smem + 24576,  t);
    __syncthreads();   // implies vmcnt(0): staged data landed

#pragma unroll
    for (int ks = 0; ks < 2; ++ks) {
      const char* Ab = smem + ks * 8192;
      const char* Bb = smem + 16384 + ks * 8192;
      bf16x8 av[4], bv[4];
#pragma unroll
      for (int i = 0; i < 4; ++i)
        av[i] = *(const bf16x8*)(Ab + (MROW + i * 16) * 64 + fragoff);
#pragma unroll
      for (int i = 0; i < 4; ++i)
        bv[i] = *(const bf16x8*)(Bb + (NCOL + i * 16) * 64 + fragoff);
#pragma unroll
      for (int mm = 0; mm < 4; ++mm)
#pragma unroll
        for (int nn = 0; nn < 4; ++nn)
          acc[mm][nn] = __builtin_amdgcn_mfma_f32_16x16x32_bf16(av[mm], bv[nn],
                                                                acc[mm][nn], 0, 0, 0);
    }
  }

  // epilogue: lane holds col fixed, rows lk*4 + r consecutive
#pragma unroll
  for (int mm = 0; mm < 4; ++mm) {
    const int row = bm0 + MROW + mm * 16 + (lk << 2);
    float rs[4] = {0.f, 0.f, 0.f, 0.f};   // EPI1 row-sum partials
    float inv[4];
    if (EPI == 2) {
      const float4 rsv = *(const float4*)(RS + (size_t)bz * NTOK + row);
      inv[0] = 1.f / rsv.x; inv[1] = 1.f / rsv.y;
      inv[2] = 1.f / rsv.z; inv[3] = 1.f / rsv.w;
    }
#pragma unroll
    for (int nn = 0; nn < 4; ++nn) {
      const int col = bn0 + NCOL + nn * 16 + lr;
      f32x4 v = acc[mm][nn];
      if (EPI == 0) {
        const float bb = bias[col];
        if (col < 2 * CDIM) {
#pragma unroll
          for (int r = 0; r < 4; ++r)
            Cb[(size_t)(row + r) * ldc + col] = f2bf(v[r] + bb);
        } else {
          const int bq = row >> 11;
          const int j = row & (NTOK - 1);
          const int c2 = col - 2 * CDIM;
          uint2 pk;
          pk.x = (u32)f2bf(v[0] + bb) | ((u32)f2bf(v[1] + bb) << 16);
          pk.y = (u32)f2bf(v[2] + bb) | ((u32)f2bf(v[3] + bb) << 16);
          *(uint2*)&VT[((size_t)bq * CDIM + c2) * NTOK + j] = pk;
        }
      } else if (EPI == 1) {
        // P~ = exp(s*scale + pos), unnormalized (scores bounded ~|8|, no max needed)
        u16* Cp = Cb + (size_t)bz * sC;
#pragma unroll
        for (int r = 0; r < 4; ++r) {
          float sv = v[r] * SM_SCALE + pos[(size_t)(row + r) * NTOK + col];
          float e = __expf(sv);
          rs[r] += e;
          Cp[(size_t)(row + r) * ldc + col] = f2bf(e);
        }
      } else {
        float* o = CT + (size_t)bz * sCT + (size_t)col * NTOK + row;
        f32x4 w;
        w[0] = v[0] * inv[0]; w[1] = v[1] * inv[1];
        w[2] = v[2] * inv[2]; w[3] = v[3] * inv[3];
        *(f32x4*)o = w;
      }
    }
    if (EPI == 1) {
      // reduce rs over the 16 lr-lanes, then one atomic per row
#pragma unroll
      for (int r = 0; r < 4; ++r) {
#pragma unroll
        for (int mk = 1; mk <= 8; mk <<= 1)
          rs[r] += __shfl_xor(rs[r], mk, 64);
      }
      if (lr == 0) {
        float* rp = RS + (size_t)bz * NTOK + row;
        atomicAdd(rp + 0, rs[0]);
        atomicAdd(rp + 1, rs[1]);
        atomicAdd(rp + 2, rs[2]);
        atomicAdd(rp + 3, rs[3]);
      }
    }
  }
}

extern "C" void kernel_launch(void* const* d_in, const int* in_sizes, int n_in,
                              void* d_out, int out_size, void* d_ws, size_t ws_size,
                              hipStream_t stream) {
  const float* x     = (const float*)d_in[0];
  const float* pos   = (const float*)d_in[1];
  const float* gamma = (const float*)d_in[2];
  const float* beta  = (const float*)d_in[3];
  const float* W     = (const float*)d_in[4];
  const float* bias  = (const float*)d_in[5];
  float* out = (float*)d_out;
  char* ws = (char*)d_ws;

  // workspace layout (118 MB total)
  u16* Wb  = (u16*)(ws);                  //  6 MB  [3072,1024] bf16 (dead after QKV)
  u16* h   = (u16*)(ws + (6ll << 20));    // 16 MB  [8192,1024] bf16
  u16* qkv = (u16*)(ws + (22ll << 20));   // 48 MB  [8192,3072] bf16 (q,k cols used)
  u16* vT  = (u16*)(ws + (70ll << 20));   // 16 MB  [4][1024][2048] bf16
  u16* S   = (u16*)(ws + (86ll << 20));   // 32 MB  [4][2048][2048] bf16 (P~ after QK^T)
  float* RS = (float*)ws;                 // 32 KB row sums, overlays dead Wb region

  wconv_kernel<<<dim3((QKVD * CDIM / 8 + 255) / 256), 256, 0, stream>>>(W, Wb, QKVD * CDIM / 8);
  ln_kernel<<<dim3(BSZ * (NTOK / 32)), 512, 0, stream>>>(x, gamma, beta, h);

  // qkv = h @ W^T + b  (M=8192, N=3072, K=1024); v written transposed into vT
  gemm_kernel<0><<<dim3(MTOT / 128, QKVD / 128, 1), 256, 0, stream>>>(
      h, CDIM, 0, Wb, CDIM, 0, CDIM,
      bias, nullptr, qkv, QKVD, 0, vT, nullptr, 0, nullptr);

  // Wb dead now; reuse its first 32KB for row sums
  zero_kernel<<<dim3(MTOT / 256), 256, 0, stream>>>(RS, MTOT);

  // P~ = exp(q @ k^T * scale + position), row sums -> RS (per batch M=N=2048, K=1024)
  gemm_kernel<1><<<dim3(NTOK / 128, NTOK / 128, BSZ), 256, 0, stream>>>(
      qkv, QKVD, (long)NTOK * QKVD, qkv + CDIM, QKVD, (long)NTOK * QKVD, CDIM,
      nullptr, pos, S, NTOK, (long)NTOK * NTOK, nullptr, nullptr, 0, RS);

  // out = (P~ @ vT^T) / rowsum, written transposed to [B, C, N] f32
  gemm_kernel<2><<<dim3(NTOK / 128, CDIM / 128, BSZ), 256, 0, stream>>>(
      S, NTOK, (long)NTOK * NTOK, vT, NTOK, (long)CDIM * NTOK, NTOK,
      nullptr, nullptr, nullptr, 0, 0, nullptr, out, (long)CDIM * NTOK, RS);
}